// Round 6
// baseline (1037.691 us; speedup 1.0000x reference)
//
#include <hip/hip_runtime.h>
#include <stdint.h>

typedef __attribute__((ext_vector_type(8))) short short8;
typedef __attribute__((ext_vector_type(4))) float floatx4;

#define T1 127
#define ENC 256
#define HD 256

// workspace offsets (bytes)
#define D0_OFF    1048576u      // 512*128 u64 = 524288  (epoch-tagged d words)
#define D1_OFF    1572864u
#define WEFF_OFF  2097152u      // 256 floats
#define YT_OFF    2099200u      // 512*128 fp32 = 262144
#define CTX_OFF   2361344u      // 512*256 fp32 = 524288
#define DT_OFF    2885632u      // 512*256 fp32 = 524288

__device__ __forceinline__ void split_bf16(float x, unsigned& hi, unsigned& lo) {
    unsigned u = __float_as_uint(x);
    hi = u >> 16;
    float hf = __uint_as_float(hi << 16);
    float r = x - hf;
    unsigned ur = __float_as_uint(r);
    lo = (ur + 0x7fffu + ((ur >> 16) & 1u)) >> 16;
}

__device__ __forceinline__ float sigm_f(float x) { return 1.f / (1.f + __expf(-x)); }
__device__ __forceinline__ float tanh_f(float x) {
    x = fminf(9.f, fmaxf(-9.f, x));
    float e = __expf(2.f * x);
    return (e - 1.f) / (e + 1.f);
}

// ---------------- k_prep: D0 zero + weff collapse ----------------
__global__ __launch_bounds__(256) void k_prep(const float* __restrict__ W1,
                                              const float* __restrict__ W2,
                                              char* __restrict__ ws) {
    const int tid = threadIdx.x, bid = blockIdx.x;
    {
        const int idx = bid * 256 + tid;
        if (idx < 32768) ((uint4*)(ws + D0_OFF))[idx] = make_uint4(0, 0, 0, 0);
    }
    if (bid == 0) {
        float acc = 0.f;
        for (int j = 0; j < 128; ++j)
            acc = fmaf(W2[j], W1[j * 768 + 512 + tid], acc);
        ((float*)(ws + WEFF_OFF))[tid] = acc;
    }
}

// ---------------- k_attn (R14-proven): scores -> softmax -> context -> y_tilde ----------------
__global__ __launch_bounds__(512) void k_attn(const float* __restrict__ X,
                                              const float* __restrict__ y_prev,
                                              const float* __restrict__ W_fc,
                                              const float* __restrict__ b_fc,
                                              char* __restrict__ ws) {
    __shared__ float s_lds[128];
    __shared__ float beta[128];
    __shared__ float part[512];
    __shared__ float wsum[8];
    __shared__ float su;
    const int b = blockIdx.x, tid = threadIdx.x;
    const int w = tid >> 6, lane = tid & 63;
    const float* Xb = X + (size_t)b * T1 * ENC;
    const float* weff = (const float*)(ws + WEFF_OFF);
    const float4 w4 = ((const float4*)weff)[lane];
    #pragma unroll 4
    for (int i = 0; i < 16; ++i) {
        int t = w * 16 + i;
        if (t >= T1) break;
        float4 x4 = ((const float4*)(Xb + t * ENC))[lane];
        float a = x4.x * w4.x + x4.y * w4.y + x4.z * w4.z + x4.w * w4.w;
        for (int m = 32; m >= 1; m >>= 1) a += __shfl_xor(a, m, 64);
        if (lane == 0) s_lds[t] = a;
    }
    __syncthreads();
    if (w == 0) {
        float v0 = s_lds[lane];
        float v1 = (lane + 64 < T1) ? s_lds[lane + 64] : -1e30f;
        float mx = fmaxf(v0, v1);
        for (int m = 32; m >= 1; m >>= 1) mx = fmaxf(mx, __shfl_xor(mx, m, 64));
        float e0 = __expf(v0 - mx);
        float e1 = (lane + 64 < T1) ? __expf(v1 - mx) : 0.f;
        float s = e0 + e1;
        for (int m = 32; m >= 1; m >>= 1) s += __shfl_xor(s, m, 64);
        float inv = 1.f / s;
        beta[lane] = e0 * inv;
        if (lane + 64 < T1) beta[lane + 64] = e1 * inv;
    }
    __syncthreads();
    {
        const int col = tid & 255, half = tid >> 8;
        const int t0 = half * 64;
        const int tend = half ? T1 : 64;
        float acc = 0.f;
        for (int t = t0; t < tend; ++t) acc = fmaf(beta[t], Xb[t * ENC + col], acc);
        part[half * 256 + col] = acc;
    }
    __syncthreads();
    float v = 0.f;
    if (tid < 256) {
        float ctx = part[tid] + part[256 + tid];
        ((float*)(ws + CTX_OFF))[b * ENC + tid] = ctx;
        v = ctx * W_fc[tid];
    }
    for (int m = 32; m >= 1; m >>= 1) v += __shfl_xor(v, m, 64);
    if (lane == 0) wsum[w] = v;
    __syncthreads();
    if (tid == 0)
        su = wsum[0] + wsum[1] + wsum[2] + wsum[3] + b_fc[0];
    __syncthreads();
    const float wy = W_fc[256];
    if (tid < T1)
        ((float*)(ws + YT_OFF))[b * 128 + tid] = su + wy * y_prev[b * T1 + tid];
}

// ---------------- k_lstm: wave-autonomous register-poll LSTM ----------------
// R16: same 256-block cross-XCD topology, same epoch-in-data word format and
// 2-buffer/4-epoch protocol as the proven 410 us kernel. NEW consumer side:
// each wave polls the FULL d-set directly into registers (16 dwordx4 in one asm,
// all epoch bits validated in-register), decodes to MFMA A-frags, runs its own
// 2 N-tiles, transposes gates wave-locally through a private LDS patch
// (lgkmcnt-ordered, no barrier), updates its own 8 h-cells x 16 batches, and
// publishes its own 64 d-words (1 per lane). ZERO __syncthreads in the t-loop —
// waves are independent agents; block-wide max-of-224 poll coupling is gone.
// Own-slice data flows through the same global path as remote (latency equal to
// the remote max it must wait for anyway). Producer overwrite safety: publish of
// step t+2 is gated on this wave's full poll of t+1, which requires every other
// wave to have published t+1, which required them to have consumed t. (Same
// slack-1 argument as the proven kernel, now per-wave.)
__global__ __launch_bounds__(256, 1) void k_lstm(const float* __restrict__ W_ih,
                                                 const float* __restrict__ b_ih,
                                                 const float* __restrict__ b_hh,
                                                 const float* __restrict__ W_hh,
                                                 char* __restrict__ ws) {
    __shared__ float gbufw[4][16 * 36];   // per-wave gate transpose patch

    const int tid = threadIdx.x, bid = blockIdx.x;
    const int gi = bid >> 3, hj = bid & 7;
    const int w = tid >> 6, lane = tid & 63;
    const int n16 = lane & 15, q = lane >> 4;

    unsigned long long* Dbuf0 = (unsigned long long*)(ws + D0_OFF);
    unsigned long long* Dbuf1 = (unsigned long long*)(ws + D1_OFF);
    const float* yt = (const float*)(ws + YT_OFF);
    float* dT = (float*)(ws + DT_OFF);

    // resident W fragments (inline hi/lo split): wave w owns N-tiles {2w, 2w+1}
    short8 bfh[2][8], bfl[2][8];
    #pragma unroll
    for (int j = 0; j < 2; ++j) {
        const int r = (2 * w + j) * 16 + n16;          // 0..127
        const int hloc = r >> 2, g = r & 3;
        const int R = g * 256 + hj * 32 + hloc;        // global gate row
        #pragma unroll
        for (int kt = 0; kt < 8; ++kt) {
            const float* src = W_hh + R * 256 + kt * 32 + q * 8;
            float4 f0 = ((const float4*)src)[0];
            float4 f1 = ((const float4*)src)[1];
            float vv[8] = {f0.x, f0.y, f0.z, f0.w, f1.x, f1.y, f1.z, f1.w};
            unsigned h[8], l[8];
            #pragma unroll
            for (int i = 0; i < 8; ++i) split_bf16(vv[i], h[i], l[i]);
            short8 sh, sl;
            #pragma unroll
            for (int i = 0; i < 8; ++i) { sh[i] = (short)h[i]; sl[i] = (short)l[i]; }
            bfh[j][kt] = sh;
            bfl[j][kt] = sl;
        }
    }

    // cell assignment (wave-local): lane (q,n16) -> batch b_loc = q*4 + (n16&3),
    // cells hlA = 8w + (n16>>2) and hlB = hlA + 4 (block-local h)
    const int jb = n16 & 3, sa = n16 >> 2;
    const int b_loc = q * 4 + jb;
    const int bg = gi * 16 + b_loc;
    const int hlA = 8 * w + sa, hlB = hlA + 4;
    float wihr[2][4], bihr[2][4];
    #pragma unroll
    for (int g = 0; g < 4; ++g) {
        const int rowA = g * HD + hj * 32 + hlA;
        const int rowB = g * HD + hj * 32 + hlB;
        wihr[0][g] = W_ih[rowA]; bihr[0][g] = b_ih[rowA] + b_hh[rowA];
        wihr[1][g] = W_ih[rowB]; bihr[1][g] = b_ih[rowB] + b_hh[rowB];
    }
    float cc0 = 0.f, cc1 = 0.f;

    // poll: lane reads batch-line (gi*16 + n16), words kt*16 + q*4 + {0..3} for kt 0..7
    const size_t base_w = (size_t)(gi * 16 + n16) * 128 + q * 4;

    // publish: lane owns word (batch b_loc, hpair) — see pairing via shfl_xor(4)
    const int hpair = (sa & 1) ? (4 * w + 2 + (sa >> 1)) : (4 * w + (sa >> 1));
    const size_t pub_idx = (size_t)bg * 128 + hj * 16 + hpair;

    float* gb = gbufw[w];

    for (int t = 1; t <= T1; ++t) {
        const float ytv = yt[bg * 128 + (t - 1)];
        unsigned long long* Dsrc = ((t - 1) & 1) ? Dbuf1 : Dbuf0;
        const unsigned e  = (unsigned)(t - 1) & 3u;
        const unsigned eh = e >> 1;
        const unsigned long long addr = (unsigned long long)(Dsrc + base_w);
        uint4 a0, b0, a1, b1, a2, b2, a3, b3, a4, b4, a5, b5, a6, b6, a7, b7;
        for (int round = 0; ; ++round) {
            asm volatile(
                "global_load_dwordx4 %0, %16, off sc0 sc1\n\t"
                "global_load_dwordx4 %1, %16, off offset:16 sc0 sc1\n\t"
                "global_load_dwordx4 %2, %16, off offset:128 sc0 sc1\n\t"
                "global_load_dwordx4 %3, %16, off offset:144 sc0 sc1\n\t"
                "global_load_dwordx4 %4, %16, off offset:256 sc0 sc1\n\t"
                "global_load_dwordx4 %5, %16, off offset:272 sc0 sc1\n\t"
                "global_load_dwordx4 %6, %16, off offset:384 sc0 sc1\n\t"
                "global_load_dwordx4 %7, %16, off offset:400 sc0 sc1\n\t"
                "global_load_dwordx4 %8, %16, off offset:512 sc0 sc1\n\t"
                "global_load_dwordx4 %9, %16, off offset:528 sc0 sc1\n\t"
                "global_load_dwordx4 %10, %16, off offset:640 sc0 sc1\n\t"
                "global_load_dwordx4 %11, %16, off offset:656 sc0 sc1\n\t"
                "global_load_dwordx4 %12, %16, off offset:768 sc0 sc1\n\t"
                "global_load_dwordx4 %13, %16, off offset:784 sc0 sc1\n\t"
                "global_load_dwordx4 %14, %16, off offset:896 sc0 sc1\n\t"
                "global_load_dwordx4 %15, %16, off offset:912 sc0 sc1\n\t"
                "s_waitcnt vmcnt(0)"
                : "=&v"(a0), "=&v"(b0), "=&v"(a1), "=&v"(b1),
                  "=&v"(a2), "=&v"(b2), "=&v"(a3), "=&v"(b3),
                  "=&v"(a4), "=&v"(b4), "=&v"(a5), "=&v"(b5),
                  "=&v"(a6), "=&v"(b6), "=&v"(a7), "=&v"(b7)
                : "v"(addr) : "memory");
            unsigned bad = 0;
#define CHK(A, B) bad |= (A.x ^ e) | (A.z ^ e) | (B.x ^ e) | (B.z ^ e) | \
                         (A.y ^ eh) | (A.w ^ eh) | (B.y ^ eh) | (B.w ^ eh)
            CHK(a0, b0); CHK(a1, b1); CHK(a2, b2); CHK(a3, b3);
            CHK(a4, b4); CHK(a5, b5); CHK(a6, b6); CHK(a7, b7);
#undef CHK
            if (__all((bad & 1u) == 0u)) break;
            if (round >= 8) __builtin_amdgcn_s_sleep(1);
        }
        // decode + MFMA, per k-tile (hi*hi + lo*hi + hi*lo)
        floatx4 acc0 = {0.f, 0.f, 0.f, 0.f}, acc1 = {0.f, 0.f, 0.f, 0.f};
#define KT(A, B, kt) { \
            union { int4 i; short8 s; } uh_, ul_; \
            uh_.i.x = (int)((A.y & 0xffff0000u) | (A.x >> 16)); \
            uh_.i.y = (int)((A.w & 0xffff0000u) | (A.z >> 16)); \
            uh_.i.z = (int)((B.y & 0xffff0000u) | (B.x >> 16)); \
            uh_.i.w = (int)((B.w & 0xffff0000u) | (B.z >> 16)); \
            ul_.i.x = (int)(((A.y & 0xfffeu) << 16) | (A.x & 0xfffeu)); \
            ul_.i.y = (int)(((A.w & 0xfffeu) << 16) | (A.z & 0xfffeu)); \
            ul_.i.z = (int)(((B.y & 0xfffeu) << 16) | (B.x & 0xfffeu)); \
            ul_.i.w = (int)(((B.w & 0xfffeu) << 16) | (B.z & 0xfffeu)); \
            acc0 = __builtin_amdgcn_mfma_f32_16x16x32_bf16(uh_.s, bfh[0][kt], acc0, 0, 0, 0); \
            acc0 = __builtin_amdgcn_mfma_f32_16x16x32_bf16(ul_.s, bfh[0][kt], acc0, 0, 0, 0); \
            acc0 = __builtin_amdgcn_mfma_f32_16x16x32_bf16(uh_.s, bfl[0][kt], acc0, 0, 0, 0); \
            acc1 = __builtin_amdgcn_mfma_f32_16x16x32_bf16(uh_.s, bfh[1][kt], acc1, 0, 0, 0); \
            acc1 = __builtin_amdgcn_mfma_f32_16x16x32_bf16(ul_.s, bfh[1][kt], acc1, 0, 0, 0); \
            acc1 = __builtin_amdgcn_mfma_f32_16x16x32_bf16(uh_.s, bfl[1][kt], acc1, 0, 0, 0); }
        KT(a0, b0, 0); KT(a1, b1, 1); KT(a2, b2, 2); KT(a3, b3, 3);
        KT(a4, b4, 4); KT(a5, b5, 5); KT(a6, b6, 6); KT(a7, b7, 7);
#undef KT
        // wave-local gate transpose through private LDS patch (no block barrier)
        #pragma unroll
        for (int reg = 0; reg < 4; ++reg) {
            gb[(q * 4 + reg) * 36 + n16]      = acc0[reg];
            gb[(q * 4 + reg) * 36 + 16 + n16] = acc1[reg];
        }
        asm volatile("s_waitcnt lgkmcnt(0)" ::: "memory");
        float4 gA = *(const float4*)&gb[b_loc * 36 + sa * 4];
        float4 gB = *(const float4*)&gb[b_loc * 36 + 16 + sa * 4];
        // LSTM cell x2
        float dn0, dn1;
        {
            float pi = gA.x + ytv * wihr[0][0] + bihr[0][0];
            float pf = gA.y + ytv * wihr[0][1] + bihr[0][1];
            float pg = gA.z + ytv * wihr[0][2] + bihr[0][2];
            float po = gA.w + ytv * wihr[0][3] + bihr[0][3];
            float ig = sigm_f(pi), fg = sigm_f(pf), og = sigm_f(po);
            cc0 = fg * cc0 + ig * tanh_f(pg);
            dn0 = og * tanh_f(cc0);
        }
        {
            float pi = gB.x + ytv * wihr[1][0] + bihr[1][0];
            float pf = gB.y + ytv * wihr[1][1] + bihr[1][1];
            float pg = gB.z + ytv * wihr[1][2] + bihr[1][2];
            float po = gB.w + ytv * wihr[1][3] + bihr[1][3];
            float ig = sigm_f(pi), fg = sigm_f(pf), og = sigm_f(po);
            cc1 = fg * cc1 + ig * tanh_f(pg);
            dn1 = og * tanh_f(cc1);
        }
        // pair-exchange across sa^1 (lane xor 4): even-sa lanes publish the acc0
        // hpair, odd-sa lanes the acc1 hpair — 1 word per lane, 64 words per wave
        float r0 = __shfl_xor(dn0, 4, 64);
        float r1 = __shfl_xor(dn1, 4, 64);
        float de, do_;
        if (sa & 1) { de = r1; do_ = dn1; } else { de = dn0; do_ = r0; }
        if (t < T1) {
            const unsigned ep = (unsigned)t & 3u;
            unsigned he, le, ho, lo_;
            split_bf16(de, he, le);
            split_bf16(do_, ho, lo_);
            le  = (le  & 0xFFFEu) | (ep & 1u);
            lo_ = (lo_ & 0xFFFEu) | ((ep >> 1) & 1u);
            unsigned long long wv = ((unsigned long long)ho << 48) |
                                    ((unsigned long long)lo_ << 32) |
                                    ((unsigned long long)he << 16) |
                                    (unsigned long long)le;
            unsigned long long* Ddst = (t & 1) ? Dbuf1 : Dbuf0;
            __hip_atomic_store(&Ddst[pub_idx], wv, __ATOMIC_RELAXED,
                               __HIP_MEMORY_SCOPE_AGENT);
        } else {
            *(float2*)(dT + (size_t)bg * 256 + hj * 32 + 2 * hpair) =
                make_float2(de, do_);
        }
    }
}

// ---------------- k_final: y_pred = W_final . [dT, context] + b ----------------
__global__ __launch_bounds__(256) void k_final(const float* __restrict__ W_final,
                                               const float* __restrict__ b_final,
                                               float* __restrict__ out,
                                               char* __restrict__ ws) {
    __shared__ float red[256];
    const int b = blockIdx.x, tid = threadIdx.x;
    const float* dT = (const float*)(ws + DT_OFF);
    const float* ctx = (const float*)(ws + CTX_OFF);
    float v = W_final[tid] * dT[b * 256 + tid] + W_final[256 + tid] * ctx[b * 256 + tid];
    red[tid] = v;
    __syncthreads();
    for (int s = 128; s >= 1; s >>= 1) { if (tid < s) red[tid] += red[tid + s]; __syncthreads(); }
    if (tid == 0) out[b] = red[0] + b_final[0];
}

extern "C" void kernel_launch(void* const* d_in, const int* in_sizes, int n_in,
                              void* d_out, int out_size, void* d_ws, size_t ws_size,
                              hipStream_t stream) {
    const float* X      = (const float*)d_in[0];
    const float* y_prev = (const float*)d_in[1];
    const float* W1     = (const float*)d_in[2];
    const float* W2     = (const float*)d_in[4];
    const float* W_fc   = (const float*)d_in[6];
    const float* b_fc   = (const float*)d_in[7];
    const float* W_ih   = (const float*)d_in[8];
    const float* W_hh   = (const float*)d_in[9];
    const float* b_ih   = (const float*)d_in[10];
    const float* b_hh   = (const float*)d_in[11];
    const float* W_fin  = (const float*)d_in[12];
    const float* b_fin  = (const float*)d_in[13];
    char* ws = (char*)d_ws;

    hipLaunchKernelGGL(k_prep,  dim3(128), dim3(256), 0, stream, W1, W2, ws);
    hipLaunchKernelGGL(k_attn,  dim3(512), dim3(512), 0, stream, X, y_prev, W_fc, b_fc, ws);
    hipLaunchKernelGGL(k_lstm,  dim3(256), dim3(256), 0, stream, W_ih, b_ih, b_hh, W_hh, ws);
    hipLaunchKernelGGL(k_final, dim3(512), dim3(256), 0, stream, W_fin, b_fin, (float*)d_out, ws);
}

// Round 8
// 565.704 us; speedup vs baseline: 1.8343x; 1.8343x over previous
//
#include <hip/hip_runtime.h>
#include <stdint.h>

typedef __attribute__((ext_vector_type(8))) short short8;
typedef __attribute__((ext_vector_type(8))) unsigned short ushort8_t;
typedef __attribute__((ext_vector_type(4))) float floatx4;

#define T1 127
#define ENC 256
#define HD 256

// workspace offsets (bytes)
#define D0_OFF    1048576u      // 512*128 u64 = 524288  (epoch-tagged d words)
#define D1_OFF    1572864u
#define YT_OFF    2099200u      // 512*128 fp32 = 262144

__device__ __forceinline__ void split_bf16(float x, unsigned& hi, unsigned& lo) {
    unsigned u = __float_as_uint(x);
    hi = u >> 16;
    float hf = __uint_as_float(hi << 16);
    float r = x - hf;
    unsigned ur = __float_as_uint(r);
    lo = (ur + 0x7fffu + ((ur >> 16) & 1u)) >> 16;
}

__device__ __forceinline__ float sigm_f(float x) { return 1.f / (1.f + __expf(-x)); }
__device__ __forceinline__ float tanh_f(float x) {
    x = fminf(9.f, fmaxf(-9.f, x));
    float e = __expf(2.f * x);
    return (e - 1.f) / (e + 1.f);
}

// One 64-B line sample, agent-coherent (sc0 sc1: bypass L1+L2, served at IC/HBM).
// All 8 u64 words of a thread's poll octet live in this single aligned line and
// are written by one producer wave; per-8B atomicity holds (8-B stores), epoch
// bits are validated per word.
__device__ __forceinline__ void load64_ag(const unsigned long long* p,
                                          uint4& a, uint4& b, uint4& c, uint4& d) {
    asm volatile("global_load_dwordx4 %0, %4, off sc0 sc1\n\t"
                 "global_load_dwordx4 %1, %4, off offset:16 sc0 sc1\n\t"
                 "global_load_dwordx4 %2, %4, off offset:32 sc0 sc1\n\t"
                 "global_load_dwordx4 %3, %4, off offset:48 sc0 sc1\n\t"
                 "s_waitcnt vmcnt(0)"
                 : "=v"(a), "=v"(b), "=v"(c), "=v"(d)
                 : "v"((unsigned long long)p)
                 : "memory");
}

// ---------------- k_attn: weff in-block + scores -> softmax -> context -> y_tilde + out-seed ----------------
// R18: k_prep's weff collapse moved here (identical FMA order -> bit-identical);
// adds the W_final[256:]·ctx reduction and seeds out[b] = that + b_final (k_final's
// ctx half). CTX is no longer materialized anywhere.
__global__ __launch_bounds__(512) void k_attn(const float* __restrict__ X,
                                              const float* __restrict__ y_prev,
                                              const float* __restrict__ W1,
                                              const float* __restrict__ W2,
                                              const float* __restrict__ W_fc,
                                              const float* __restrict__ b_fc,
                                              const float* __restrict__ W_final,
                                              const float* __restrict__ b_final,
                                              float* __restrict__ out,
                                              char* __restrict__ ws) {
    __shared__ float s_lds[128];
    __shared__ float beta[128];
    __shared__ float part[512];
    __shared__ float wsum[8];
    __shared__ float fsum[8];
    __shared__ float su;
    const int b = blockIdx.x, tid = threadIdx.x;
    const int w = tid >> 6, lane = tid & 63;
    const float* Xb = X + (size_t)b * T1 * ENC;
    // weff components for this lane (k_prep's exact loop order -> same rounding)
    float4 w4; w4.x = w4.y = w4.z = w4.w = 0.f;
    {
        const float* W1c = W1 + 512 + lane * 4;
        #pragma unroll 4
        for (int j = 0; j < 128; ++j) {
            const float s = W2[j];
            const float4 c = *(const float4*)(W1c + j * 768);
            w4.x = fmaf(s, c.x, w4.x);
            w4.y = fmaf(s, c.y, w4.y);
            w4.z = fmaf(s, c.z, w4.z);
            w4.w = fmaf(s, c.w, w4.w);
        }
    }
    #pragma unroll 4
    for (int i = 0; i < 16; ++i) {
        int t = w * 16 + i;
        if (t >= T1) break;
        float4 x4 = ((const float4*)(Xb + t * ENC))[lane];
        float a = x4.x * w4.x + x4.y * w4.y + x4.z * w4.z + x4.w * w4.w;
        for (int m = 32; m >= 1; m >>= 1) a += __shfl_xor(a, m, 64);
        if (lane == 0) s_lds[t] = a;
    }
    __syncthreads();
    if (w == 0) {
        float v0 = s_lds[lane];
        float v1 = (lane + 64 < T1) ? s_lds[lane + 64] : -1e30f;
        float mx = fmaxf(v0, v1);
        for (int m = 32; m >= 1; m >>= 1) mx = fmaxf(mx, __shfl_xor(mx, m, 64));
        float e0 = __expf(v0 - mx);
        float e1 = (lane + 64 < T1) ? __expf(v1 - mx) : 0.f;
        float s = e0 + e1;
        for (int m = 32; m >= 1; m >>= 1) s += __shfl_xor(s, m, 64);
        float inv = 1.f / s;
        beta[lane] = e0 * inv;
        if (lane + 64 < T1) beta[lane + 64] = e1 * inv;
    }
    __syncthreads();
    {
        const int col = tid & 255, half = tid >> 8;
        const int t0 = half * 64;
        const int tend = half ? T1 : 64;
        float acc = 0.f;
        for (int t = t0; t < tend; ++t) acc = fmaf(beta[t], Xb[t * ENC + col], acc);
        part[half * 256 + col] = acc;
    }
    __syncthreads();
    float v = 0.f, vf = 0.f;
    if (tid < 256) {
        float ctx = part[tid] + part[256 + tid];
        v  = ctx * W_fc[tid];
        vf = ctx * W_final[256 + tid];
    }
    for (int m = 32; m >= 1; m >>= 1) {
        v  += __shfl_xor(v, m, 64);
        vf += __shfl_xor(vf, m, 64);
    }
    if (lane == 0) { wsum[w] = v; fsum[w] = vf; }
    __syncthreads();
    if (tid == 0) {
        su = wsum[0] + wsum[1] + wsum[2] + wsum[3] + b_fc[0];
        out[b] = fsum[0] + fsum[1] + fsum[2] + fsum[3] + b_final[0];
    }
    __syncthreads();
    const float wy = W_fc[256];
    if (tid < T1)
        ((float*)(ws + YT_OFF))[b * 128 + tid] = su + wy * y_prev[b * T1 + tid];
}

// ---------------- k_lstm: persistent sequential LSTM, epoch-in-data exchange ----------------
// Proven R10 t-loop, byte-identical (256 blocks, gi = bid>>3, hj = bid&7, serial
// 64-B line poll, two __syncthreads, publish-first). R18 deltas are OUTSIDE the
// loop only: (a) prologue self-zeroes this block's own D0 publish slice (replaces
// k_prep's zeroing; consumers' t=1 polls wait for the zeros via the epoch check —
// leftover D0 words carry epoch-2 tags from the prior run's t=126, so no false
// match); (b) W_hh hi/lo split inline at fragment load (R16-proven); (c) epilogue
// replaces the dT store with atomicAdd(out+bg, dnew·W_final[h]) — k_final's dT
// half folded in (out was seeded by k_attn, which the kernel boundary orders).
__global__ __launch_bounds__(256, 1) void k_lstm(const float* __restrict__ W_ih,
                                                 const float* __restrict__ b_ih,
                                                 const float* __restrict__ b_hh,
                                                 const float* __restrict__ W_hh,
                                                 const float* __restrict__ W_final,
                                                 float* __restrict__ out,
                                                 char* __restrict__ ws) {
    __shared__ __align__(16) ushort ldh[16 * 264];
    __shared__ __align__(16) ushort ldl[16 * 264];
    __shared__ float gbuf[16 * 132];

    const int tid = threadIdx.x, bid = blockIdx.x;
    const int gi = bid >> 3, hj = bid & 7;
    const int w = tid >> 6, lane = tid & 63;
    const int n16 = lane & 15, q = lane >> 4;

    unsigned long long* Dbuf0 = (unsigned long long*)(ws + D0_OFF);
    unsigned long long* Dbuf1 = (unsigned long long*)(ws + D1_OFF);
    const float* yt = (const float*)(ws + YT_OFF);

    // cell assignment: 16 batches x 32 h = 512 cells, 2 per thread
    const int b_loc = tid & 15, hpair = tid >> 4;      // hpair 0..15
    const int hloc0 = hpair * 2;
    const int bg = gi * 16 + b_loc;

    // self-zero this block's OWN publish slice in D0 (epoch-0 zeros) — earliest
    // possible visibility; consumers self-synchronize via the epoch protocol.
    __hip_atomic_store(&Dbuf0[(size_t)bg * 128 + hj * 16 + hpair], 0ull,
                       __ATOMIC_RELAXED, __HIP_MEMORY_SCOPE_AGENT);

    // resident W fragments (inline hi/lo split): wave w owns N-tiles {2w, 2w+1}
    short8 bfh[2][8], bfl[2][8];
    #pragma unroll
    for (int j = 0; j < 2; ++j) {
        const int r = (2 * w + j) * 16 + n16;          // 0..127
        const int hloc = r >> 2, g = r & 3;
        const int R = g * 256 + hj * 32 + hloc;        // global gate row
        #pragma unroll
        for (int kt = 0; kt < 8; ++kt) {
            const float* src = W_hh + R * 256 + kt * 32 + q * 8;
            float4 f0 = ((const float4*)src)[0];
            float4 f1 = ((const float4*)src)[1];
            float vv[8] = {f0.x, f0.y, f0.z, f0.w, f1.x, f1.y, f1.z, f1.w};
            unsigned h[8], l[8];
            #pragma unroll
            for (int i = 0; i < 8; ++i) split_bf16(vv[i], h[i], l[i]);
            short8 sh, sl;
            #pragma unroll
            for (int i = 0; i < 8; ++i) { sh[i] = (short)h[i]; sl[i] = (short)l[i]; }
            bfh[j][kt] = sh;
            bfl[j][kt] = sl;
        }
    }

    float wihr[2][4], bihr[2][4];
    #pragma unroll
    for (int jj = 0; jj < 2; ++jj)
        #pragma unroll
        for (int g = 0; g < 4; ++g) {
            const int row = g * HD + hj * 32 + hloc0 + jj;
            wihr[jj][g] = W_ih[row];
            bihr[jj][g] = b_ih[row] + b_hh[row];
        }
    float cc0 = 0.f, cc1 = 0.f;

    // poll/stage assignment: thread covers batch pb = tid>>4, hp8 = tid&15
    // words k = hp8*8 .. hp8*8+7 (cells h = 2k, 2k+1); origin block = hp8>>1
    const int pb = tid >> 4, hp8 = tid & 15;
    const bool own = ((hp8 >> 1) == hj);
    const size_t pbase = (size_t)(gi * 16 + pb) * 128 + hp8 * 8;   // 64B-aligned line

    // pre-zero this thread's full 16-ushort slab segment (d0 = 0) in BOTH planes
    {
        ushort8_t z = {0, 0, 0, 0, 0, 0, 0, 0};
        *(ushort8_t*)(ldh + pb * 264 + hp8 * 16)     = z;
        *(ushort8_t*)(ldh + pb * 264 + hp8 * 16 + 8) = z;
        *(ushort8_t*)(ldl + pb * 264 + hp8 * 16)     = z;
        *(ushort8_t*)(ldl + pb * 264 + hp8 * 16 + 8) = z;
    }

    for (int t = 1; t <= T1; ++t) {
        const float ytv = yt[bg * 128 + (t - 1)];   // prefetch, independent of d
        // ---- poll d_{t-1}: one 64-B line sample per round ----
        if (!own) {
            unsigned long long* Dsrc = ((t - 1) & 1) ? Dbuf1 : Dbuf0;
            const unsigned e = (unsigned)(t - 1) & 3u;
            unsigned lo[8], hi[8];
            for (int round = 0; ; ++round) {
                uint4 A, B, C, D;
                load64_ag(&Dsrc[pbase], A, B, C, D);
                lo[0] = A.x; hi[0] = A.y; lo[1] = A.z; hi[1] = A.w;
                lo[2] = B.x; hi[2] = B.y; lo[3] = B.z; hi[3] = B.w;
                lo[4] = C.x; hi[4] = C.y; lo[5] = C.z; hi[5] = C.w;
                lo[6] = D.x; hi[6] = D.y; lo[7] = D.z; hi[7] = D.w;
                bool ok = true;
                #pragma unroll
                for (int i = 0; i < 8; ++i) {
                    unsigned ep = (lo[i] & 1u) | ((hi[i] & 1u) << 1);
                    ok &= (ep == e);
                }
                if (ok) break;
                if (round >= 16) __builtin_amdgcn_s_sleep(1);
            }
            // decode: 16 hi + 16 lo ushorts -> two b128 stores per plane
            ushort hv[16], lv[16];
            #pragma unroll
            for (int i = 0; i < 8; ++i) {
                hv[2 * i]     = (ushort)(lo[i] >> 16);
                hv[2 * i + 1] = (ushort)(hi[i] >> 16);
                lv[2 * i]     = (ushort)(lo[i] & 0xFFFEu);
                lv[2 * i + 1] = (ushort)(hi[i] & 0xFFFEu);
            }
            ushort8_t H0, L0, H1, L1;
            #pragma unroll
            for (int i = 0; i < 8; ++i) { H0[i] = hv[i]; L0[i] = lv[i]; H1[i] = hv[8 + i]; L1[i] = lv[8 + i]; }
            *(ushort8_t*)(ldh + pb * 264 + hp8 * 16)     = H0;
            *(ushort8_t*)(ldh + pb * 264 + hp8 * 16 + 8) = H1;
            *(ushort8_t*)(ldl + pb * 264 + hp8 * 16)     = L0;
            *(ushort8_t*)(ldl + pb * 264 + hp8 * 16 + 8) = L1;
        }
        __syncthreads();
        // MFMA: gates[16b x 128r] = d[16x256] @ Wslice^T  (hi*hi + lo*hi + hi*lo)
        floatx4 acc0 = {0.f, 0.f, 0.f, 0.f}, acc1 = {0.f, 0.f, 0.f, 0.f};
        #pragma unroll
        for (int kt = 0; kt < 8; ++kt) {
            short8 ah = *(const short8*)(ldh + n16 * 264 + kt * 32 + q * 8);
            short8 al = *(const short8*)(ldl + n16 * 264 + kt * 32 + q * 8);
            acc0 = __builtin_amdgcn_mfma_f32_16x16x32_bf16(ah, bfh[0][kt], acc0, 0, 0, 0);
            acc0 = __builtin_amdgcn_mfma_f32_16x16x32_bf16(al, bfh[0][kt], acc0, 0, 0, 0);
            acc0 = __builtin_amdgcn_mfma_f32_16x16x32_bf16(ah, bfl[0][kt], acc0, 0, 0, 0);
            acc1 = __builtin_amdgcn_mfma_f32_16x16x32_bf16(ah, bfh[1][kt], acc1, 0, 0, 0);
            acc1 = __builtin_amdgcn_mfma_f32_16x16x32_bf16(al, bfh[1][kt], acc1, 0, 0, 0);
            acc1 = __builtin_amdgcn_mfma_f32_16x16x32_bf16(ah, bfl[1][kt], acc1, 0, 0, 0);
        }
        // scatter C-frags: row m = q*4+reg (batch), col = tile*16+n16 (gate row)
        #pragma unroll
        for (int reg = 0; reg < 4; ++reg) {
            gbuf[(q * 4 + reg) * 132 + (2 * w) * 16 + n16]     = acc0[reg];
            gbuf[(q * 4 + reg) * 132 + (2 * w + 1) * 16 + n16] = acc1[reg];
        }
        __syncthreads();
        // LSTM cell: 2 cells per thread
        float dnew[2];
        #pragma unroll
        for (int jj = 0; jj < 2; ++jj) {
            const int base = b_loc * 132 + (hloc0 + jj) * 4;
            float pi = gbuf[base + 0] + ytv * wihr[jj][0] + bihr[jj][0];
            float pf = gbuf[base + 1] + ytv * wihr[jj][1] + bihr[jj][1];
            float pg = gbuf[base + 2] + ytv * wihr[jj][2] + bihr[jj][2];
            float po = gbuf[base + 3] + ytv * wihr[jj][3] + bihr[jj][3];
            float ig = sigm_f(pi), fg = sigm_f(pf), og = sigm_f(po);
            float gg = tanh_f(pg);
            float& c = jj ? cc1 : cc0;
            c = fg * c + ig * gg;
            dnew[jj] = og * tanh_f(c);
        }
        if (t < T1) {
            const unsigned e = (unsigned)t & 3u;
            unsigned h0, l0, h1, l1;
            split_bf16(dnew[0], h0, l0);
            split_bf16(dnew[1], h1, l1);
            l0 = (l0 & 0xFFFEu) | (e & 1u);
            l1 = (l1 & 0xFFFEu) | ((e >> 1) & 1u);
            // publish FIRST (earliest visibility for the 7 consumer blocks)
            unsigned long long wv = ((unsigned long long)h1 << 48) |
                                    ((unsigned long long)l1 << 32) |
                                    ((unsigned long long)h0 << 16) |
                                    (unsigned long long)l0;
            unsigned long long* Ddst = (t & 1) ? Dbuf1 : Dbuf0;
            __hip_atomic_store(&Ddst[(size_t)bg * 128 + hj * 16 + hpair], wv,
                               __ATOMIC_RELAXED, __HIP_MEMORY_SCOPE_AGENT);
            // own slice -> directly into next step's LDS slab (barrier-ordered)
            *(ushort2*)(ldh + b_loc * 264 + hj * 32 + hloc0) =
                make_ushort2((ushort)h0, (ushort)h1);
            *(ushort2*)(ldl + b_loc * 264 + hj * 32 + hloc0) =
                make_ushort2((ushort)(l0 & 0xFFFEu), (ushort)(l1 & 0xFFFEu));
        } else {
            // fused k_final (dT half): out[bg] += dnew · W_final[h]
            const float wf0 = W_final[hj * 32 + hloc0];
            const float wf1 = W_final[hj * 32 + hloc0 + 1];
            atomicAdd(out + bg, dnew[0] * wf0 + dnew[1] * wf1);
        }
    }
}

extern "C" void kernel_launch(void* const* d_in, const int* in_sizes, int n_in,
                              void* d_out, int out_size, void* d_ws, size_t ws_size,
                              hipStream_t stream) {
    const float* X      = (const float*)d_in[0];
    const float* y_prev = (const float*)d_in[1];
    const float* W1     = (const float*)d_in[2];
    const float* W2     = (const float*)d_in[4];
    const float* W_fc   = (const float*)d_in[6];
    const float* b_fc   = (const float*)d_in[7];
    const float* W_ih   = (const float*)d_in[8];
    const float* W_hh   = (const float*)d_in[9];
    const float* b_ih   = (const float*)d_in[10];
    const float* b_hh   = (const float*)d_in[11];
    const float* W_fin  = (const float*)d_in[12];
    const float* b_fin  = (const float*)d_in[13];
    char* ws = (char*)d_ws;

    hipLaunchKernelGGL(k_attn, dim3(512), dim3(512), 0, stream,
                       X, y_prev, W1, W2, W_fc, b_fc, W_fin, b_fin, (float*)d_out, ws);
    hipLaunchKernelGGL(k_lstm, dim3(256), dim3(256), 0, stream,
                       W_ih, b_ih, b_hh, W_hh, W_fin, (float*)d_out, ws);
}

// Round 9
// 545.563 us; speedup vs baseline: 1.9021x; 1.0369x over previous
//
#include <hip/hip_runtime.h>
#include <stdint.h>

typedef __attribute__((ext_vector_type(8))) short short8;
typedef __attribute__((ext_vector_type(8))) unsigned short ushort8_t;
typedef __attribute__((ext_vector_type(4))) float floatx4;

#define T1 127
#define ENC 256
#define HD 256

// workspace offsets (bytes)
#define WHI_OFF   0u            // 1024*256 ushort = 524288
#define WLO_OFF   524288u
#define D0_OFF    1048576u      // 512*128 u64 = 524288  (epoch-tagged d words)
#define D1_OFF    1572864u
#define WEFF_OFF  2097152u      // 256 floats
#define YT_OFF    2099200u      // 512*128 fp32 = 262144

__device__ __forceinline__ void split_bf16(float x, unsigned& hi, unsigned& lo) {
    unsigned u = __float_as_uint(x);
    hi = u >> 16;
    float hf = __uint_as_float(hi << 16);
    float r = x - hf;
    unsigned ur = __float_as_uint(r);
    lo = (ur + 0x7fffu + ((ur >> 16) & 1u)) >> 16;
}

__device__ __forceinline__ float sigm_f(float x) { return 1.f / (1.f + __expf(-x)); }
__device__ __forceinline__ float tanh_f(float x) {
    x = fminf(9.f, fmaxf(-9.f, x));
    float e = __expf(2.f * x);
    return (e - 1.f) / (e + 1.f);
}

// One 64-B line sample, agent-coherent (sc0 sc1: bypass L1+L2, served at IC/HBM).
// All 8 u64 words of a thread's poll octet live in this single aligned line and
// are written by one producer wave; per-8B atomicity holds (8-B stores), epoch
// bits are validated per word.
__device__ __forceinline__ void load64_ag(const unsigned long long* p,
                                          uint4& a, uint4& b, uint4& c, uint4& d) {
    asm volatile("global_load_dwordx4 %0, %4, off sc0 sc1\n\t"
                 "global_load_dwordx4 %1, %4, off offset:16 sc0 sc1\n\t"
                 "global_load_dwordx4 %2, %4, off offset:32 sc0 sc1\n\t"
                 "global_load_dwordx4 %3, %4, off offset:48 sc0 sc1\n\t"
                 "s_waitcnt vmcnt(0)"
                 : "=v"(a), "=v"(b), "=v"(c), "=v"(d)
                 : "v"((unsigned long long)p)
                 : "memory");
}

// ---------------- k_prep (R10-proven): weight collapse + W_hh hi/lo split + init ----------------
__global__ __launch_bounds__(256) void k_prep(const float* __restrict__ W1,
                                              const float* __restrict__ W2,
                                              const float* __restrict__ W_hh,
                                              char* __restrict__ ws) {
    const int tid = threadIdx.x, bid = blockIdx.x;
    ushort* Whi = (ushort*)(ws + WHI_OFF);
    ushort* Wlo = (ushort*)(ws + WLO_OFF);
    {
        const int i4 = bid * 256 + tid;   // 0..65535
        float4 v = ((const float4*)W_hh)[i4];
        float vv[4] = {v.x, v.y, v.z, v.w};
        unsigned h[4], l[4];
        #pragma unroll
        for (int j = 0; j < 4; ++j) split_bf16(vv[j], h[j], l[j]);
        *(ushort4*)(Whi + i4 * 4) = make_ushort4((ushort)h[0], (ushort)h[1], (ushort)h[2], (ushort)h[3]);
        *(ushort4*)(Wlo + i4 * 4) = make_ushort4((ushort)l[0], (ushort)l[1], (ushort)l[2], (ushort)l[3]);
    }
    {
        const int idx = bid * 256 + tid;
        if (idx < 32768) ((uint4*)(ws + D0_OFF))[idx] = make_uint4(0, 0, 0, 0);
    }
    if (bid == 0) {
        float acc = 0.f;
        for (int j = 0; j < 128; ++j)
            acc = fmaf(W2[j], W1[j * 768 + 512 + tid], acc);
        ((float*)(ws + WEFF_OFF))[tid] = acc;
    }
}

// ---------------- k_attn: scores -> softmax -> y_tilde + out-seed (ctx never stored) ----------------
// R19: R14-proven structure; adds the W_final[256:]·ctx reduction and seeds
// out[b] = that + b_final (k_final's ctx half). Context pass now runs 4
// independent fmaf chains (ILP 4) to cover the ~400-cyc IC load latency.
__global__ __launch_bounds__(512) void k_attn(const float* __restrict__ X,
                                              const float* __restrict__ y_prev,
                                              const float* __restrict__ W_fc,
                                              const float* __restrict__ b_fc,
                                              const float* __restrict__ W_final,
                                              const float* __restrict__ b_final,
                                              float* __restrict__ out,
                                              char* __restrict__ ws) {
    __shared__ float s_lds[128];
    __shared__ float beta[128];
    __shared__ float part[512];
    __shared__ float wsum[8];
    __shared__ float fsum[8];
    __shared__ float su;
    const int b = blockIdx.x, tid = threadIdx.x;
    const int w = tid >> 6, lane = tid & 63;
    const float* Xb = X + (size_t)b * T1 * ENC;
    const float* weff = (const float*)(ws + WEFF_OFF);
    const float4 w4 = ((const float4*)weff)[lane];
    #pragma unroll 4
    for (int i = 0; i < 16; ++i) {
        int t = w * 16 + i;
        if (t >= T1) break;
        float4 x4 = ((const float4*)(Xb + t * ENC))[lane];
        float a = x4.x * w4.x + x4.y * w4.y + x4.z * w4.z + x4.w * w4.w;
        for (int m = 32; m >= 1; m >>= 1) a += __shfl_xor(a, m, 64);
        if (lane == 0) s_lds[t] = a;
    }
    __syncthreads();
    if (w == 0) {
        float v0 = s_lds[lane];
        float v1 = (lane + 64 < T1) ? s_lds[lane + 64] : -1e30f;
        float mx = fmaxf(v0, v1);
        for (int m = 32; m >= 1; m >>= 1) mx = fmaxf(mx, __shfl_xor(mx, m, 64));
        float e0 = __expf(v0 - mx);
        float e1 = (lane + 64 < T1) ? __expf(v1 - mx) : 0.f;
        float s = e0 + e1;
        for (int m = 32; m >= 1; m >>= 1) s += __shfl_xor(s, m, 64);
        float inv = 1.f / s;
        beta[lane] = e0 * inv;
        if (lane + 64 < T1) beta[lane + 64] = e1 * inv;
    }
    __syncthreads();
    {
        const int col = tid & 255, half = tid >> 8;
        const int t0 = half * 64;
        const int tend = half ? T1 : 64;
        float a0 = 0.f, a1 = 0.f, a2 = 0.f, a3 = 0.f;
        int t = t0;
        for (; t + 3 < tend; t += 4) {
            a0 = fmaf(beta[t],     Xb[t * ENC + col],       a0);
            a1 = fmaf(beta[t + 1], Xb[(t + 1) * ENC + col], a1);
            a2 = fmaf(beta[t + 2], Xb[(t + 2) * ENC + col], a2);
            a3 = fmaf(beta[t + 3], Xb[(t + 3) * ENC + col], a3);
        }
        for (; t < tend; ++t) a0 = fmaf(beta[t], Xb[t * ENC + col], a0);
        part[half * 256 + col] = (a0 + a1) + (a2 + a3);
    }
    __syncthreads();
    float v = 0.f, vf = 0.f;
    if (tid < 256) {
        float ctx = part[tid] + part[256 + tid];
        v  = ctx * W_fc[tid];
        vf = ctx * W_final[256 + tid];
    }
    for (int m = 32; m >= 1; m >>= 1) {
        v  += __shfl_xor(v, m, 64);
        vf += __shfl_xor(vf, m, 64);
    }
    if (lane == 0) { wsum[w] = v; fsum[w] = vf; }
    __syncthreads();
    if (tid == 0) {
        su = wsum[0] + wsum[1] + wsum[2] + wsum[3] + b_fc[0];
        out[b] = fsum[0] + fsum[1] + fsum[2] + fsum[3] + b_final[0];
    }
    __syncthreads();
    const float wy = W_fc[256];
    if (tid < T1)
        ((float*)(ws + YT_OFF))[b * 128 + tid] = su + wy * y_prev[b * T1 + tid];
}

// ---------------- k_lstm: persistent sequential LSTM, epoch-in-data exchange ----------------
// R10-proven topology, prologue, and t-loop (byte-identical: 256 blocks,
// gi = bid>>3, hj = bid&7, Whi/Wlo staged fragments, serial 64-B line poll,
// two __syncthreads, publish-first). ONLY delta vs the 410 us kernel: the
// t = T1 epilogue replaces the dT store with atomicAdd(out+bg, dnew·W_final[h])
// (k_final's dT half; out was seeded by k_attn, ordered by the kernel boundary).
__global__ __launch_bounds__(256, 1) void k_lstm(const float* __restrict__ W_ih,
                                                 const float* __restrict__ b_ih,
                                                 const float* __restrict__ b_hh,
                                                 const float* __restrict__ W_final,
                                                 float* __restrict__ out,
                                                 char* __restrict__ ws) {
    __shared__ __align__(16) ushort ldh[16 * 264];
    __shared__ __align__(16) ushort ldl[16 * 264];
    __shared__ float gbuf[16 * 132];

    const int tid = threadIdx.x, bid = blockIdx.x;
    const int gi = bid >> 3, hj = bid & 7;
    const int w = tid >> 6, lane = tid & 63;
    const int n16 = lane & 15, q = lane >> 4;

    const ushort* Whi = (const ushort*)(ws + WHI_OFF);
    const ushort* Wlo = (const ushort*)(ws + WLO_OFF);
    unsigned long long* Dbuf0 = (unsigned long long*)(ws + D0_OFF);
    unsigned long long* Dbuf1 = (unsigned long long*)(ws + D1_OFF);
    const float* yt = (const float*)(ws + YT_OFF);

    // resident W fragments: wave w owns N-tiles {2w, 2w+1}; row r = hloc*4 + g
    short8 bfh[2][8], bfl[2][8];
    #pragma unroll
    for (int j = 0; j < 2; ++j) {
        const int r = (2 * w + j) * 16 + n16;          // 0..127
        const int hloc = r >> 2, g = r & 3;
        const int R = g * 256 + hj * 32 + hloc;        // global gate row
        #pragma unroll
        for (int kt = 0; kt < 8; ++kt) {
            bfh[j][kt] = *(const short8*)(Whi + R * 256 + kt * 32 + q * 8);
            bfl[j][kt] = *(const short8*)(Wlo + R * 256 + kt * 32 + q * 8);
        }
    }

    // cell assignment: 16 batches x 32 h = 512 cells, 2 per thread
    const int b_loc = tid & 15, hpair = tid >> 4;      // hpair 0..15
    const int hloc0 = hpair * 2;
    const int bg = gi * 16 + b_loc;
    float wihr[2][4], bihr[2][4];
    #pragma unroll
    for (int jj = 0; jj < 2; ++jj)
        #pragma unroll
        for (int g = 0; g < 4; ++g) {
            const int row = g * HD + hj * 32 + hloc0 + jj;
            wihr[jj][g] = W_ih[row];
            bihr[jj][g] = b_ih[row] + b_hh[row];
        }
    float cc0 = 0.f, cc1 = 0.f;

    // poll/stage assignment: thread covers batch pb = tid>>4, hp8 = tid&15
    // words k = hp8*8 .. hp8*8+7 (cells h = 2k, 2k+1); origin block = hp8>>1
    const int pb = tid >> 4, hp8 = tid & 15;
    const bool own = ((hp8 >> 1) == hj);
    const size_t pbase = (size_t)(gi * 16 + pb) * 128 + hp8 * 8;   // 64B-aligned line

    // pre-zero this thread's full 16-ushort slab segment (d0 = 0) in BOTH planes
    {
        ushort8_t z = {0, 0, 0, 0, 0, 0, 0, 0};
        *(ushort8_t*)(ldh + pb * 264 + hp8 * 16)     = z;
        *(ushort8_t*)(ldh + pb * 264 + hp8 * 16 + 8) = z;
        *(ushort8_t*)(ldl + pb * 264 + hp8 * 16)     = z;
        *(ushort8_t*)(ldl + pb * 264 + hp8 * 16 + 8) = z;
    }

    for (int t = 1; t <= T1; ++t) {
        const float ytv = yt[bg * 128 + (t - 1)];   // prefetch, independent of d
        // ---- poll d_{t-1}: one 64-B line sample per round ----
        if (!own) {
            unsigned long long* Dsrc = ((t - 1) & 1) ? Dbuf1 : Dbuf0;
            const unsigned e = (unsigned)(t - 1) & 3u;
            unsigned lo[8], hi[8];
            for (int round = 0; ; ++round) {
                uint4 A, B, C, D;
                load64_ag(&Dsrc[pbase], A, B, C, D);
                lo[0] = A.x; hi[0] = A.y; lo[1] = A.z; hi[1] = A.w;
                lo[2] = B.x; hi[2] = B.y; lo[3] = B.z; hi[3] = B.w;
                lo[4] = C.x; hi[4] = C.y; lo[5] = C.z; hi[5] = C.w;
                lo[6] = D.x; hi[6] = D.y; lo[7] = D.z; hi[7] = D.w;
                bool ok = true;
                #pragma unroll
                for (int i = 0; i < 8; ++i) {
                    unsigned ep = (lo[i] & 1u) | ((hi[i] & 1u) << 1);
                    ok &= (ep == e);
                }
                if (ok) break;
                if (round >= 16) __builtin_amdgcn_s_sleep(1);
            }
            // decode: 16 hi + 16 lo ushorts -> two b128 stores per plane
            ushort hv[16], lv[16];
            #pragma unroll
            for (int i = 0; i < 8; ++i) {
                hv[2 * i]     = (ushort)(lo[i] >> 16);
                hv[2 * i + 1] = (ushort)(hi[i] >> 16);
                lv[2 * i]     = (ushort)(lo[i] & 0xFFFEu);
                lv[2 * i + 1] = (ushort)(hi[i] & 0xFFFEu);
            }
            ushort8_t H0, L0, H1, L1;
            #pragma unroll
            for (int i = 0; i < 8; ++i) { H0[i] = hv[i]; L0[i] = lv[i]; H1[i] = hv[8 + i]; L1[i] = lv[8 + i]; }
            *(ushort8_t*)(ldh + pb * 264 + hp8 * 16)     = H0;
            *(ushort8_t*)(ldh + pb * 264 + hp8 * 16 + 8) = H1;
            *(ushort8_t*)(ldl + pb * 264 + hp8 * 16)     = L0;
            *(ushort8_t*)(ldl + pb * 264 + hp8 * 16 + 8) = L1;
        }
        __syncthreads();
        // MFMA: gates[16b x 128r] = d[16x256] @ Wslice^T  (hi*hi + lo*hi + hi*lo)
        floatx4 acc0 = {0.f, 0.f, 0.f, 0.f}, acc1 = {0.f, 0.f, 0.f, 0.f};
        #pragma unroll
        for (int kt = 0; kt < 8; ++kt) {
            short8 ah = *(const short8*)(ldh + n16 * 264 + kt * 32 + q * 8);
            short8 al = *(const short8*)(ldl + n16 * 264 + kt * 32 + q * 8);
            acc0 = __builtin_amdgcn_mfma_f32_16x16x32_bf16(ah, bfh[0][kt], acc0, 0, 0, 0);
            acc0 = __builtin_amdgcn_mfma_f32_16x16x32_bf16(al, bfh[0][kt], acc0, 0, 0, 0);
            acc0 = __builtin_amdgcn_mfma_f32_16x16x32_bf16(ah, bfl[0][kt], acc0, 0, 0, 0);
            acc1 = __builtin_amdgcn_mfma_f32_16x16x32_bf16(ah, bfh[1][kt], acc1, 0, 0, 0);
            acc1 = __builtin_amdgcn_mfma_f32_16x16x32_bf16(al, bfh[1][kt], acc1, 0, 0, 0);
            acc1 = __builtin_amdgcn_mfma_f32_16x16x32_bf16(ah, bfl[1][kt], acc1, 0, 0, 0);
        }
        // scatter C-frags: row m = q*4+reg (batch), col = tile*16+n16 (gate row)
        #pragma unroll
        for (int reg = 0; reg < 4; ++reg) {
            gbuf[(q * 4 + reg) * 132 + (2 * w) * 16 + n16]     = acc0[reg];
            gbuf[(q * 4 + reg) * 132 + (2 * w + 1) * 16 + n16] = acc1[reg];
        }
        __syncthreads();
        // LSTM cell: 2 cells per thread
        float dnew[2];
        #pragma unroll
        for (int jj = 0; jj < 2; ++jj) {
            const int base = b_loc * 132 + (hloc0 + jj) * 4;
            float pi = gbuf[base + 0] + ytv * wihr[jj][0] + bihr[jj][0];
            float pf = gbuf[base + 1] + ytv * wihr[jj][1] + bihr[jj][1];
            float pg = gbuf[base + 2] + ytv * wihr[jj][2] + bihr[jj][2];
            float po = gbuf[base + 3] + ytv * wihr[jj][3] + bihr[jj][3];
            float ig = sigm_f(pi), fg = sigm_f(pf), og = sigm_f(po);
            float gg = tanh_f(pg);
            float& c = jj ? cc1 : cc0;
            c = fg * c + ig * gg;
            dnew[jj] = og * tanh_f(c);
        }
        if (t < T1) {
            const unsigned e = (unsigned)t & 3u;
            unsigned h0, l0, h1, l1;
            split_bf16(dnew[0], h0, l0);
            split_bf16(dnew[1], h1, l1);
            l0 = (l0 & 0xFFFEu) | (e & 1u);
            l1 = (l1 & 0xFFFEu) | ((e >> 1) & 1u);
            // publish FIRST (earliest visibility for the 7 consumer blocks)
            unsigned long long wv = ((unsigned long long)h1 << 48) |
                                    ((unsigned long long)l1 << 32) |
                                    ((unsigned long long)h0 << 16) |
                                    (unsigned long long)l0;
            unsigned long long* Ddst = (t & 1) ? Dbuf1 : Dbuf0;
            __hip_atomic_store(&Ddst[(size_t)bg * 128 + hj * 16 + hpair], wv,
                               __ATOMIC_RELAXED, __HIP_MEMORY_SCOPE_AGENT);
            // own slice -> directly into next step's LDS slab (barrier-ordered)
            *(ushort2*)(ldh + b_loc * 264 + hj * 32 + hloc0) =
                make_ushort2((ushort)h0, (ushort)h1);
            *(ushort2*)(ldl + b_loc * 264 + hj * 32 + hloc0) =
                make_ushort2((ushort)(l0 & 0xFFFEu), (ushort)(l1 & 0xFFFEu));
        } else {
            // fused k_final (dT half): out[bg] += dnew · W_final[h]
            const float wf0 = W_final[hj * 32 + hloc0];
            const float wf1 = W_final[hj * 32 + hloc0 + 1];
            atomicAdd(out + bg, dnew[0] * wf0 + dnew[1] * wf1);
        }
    }
}

extern "C" void kernel_launch(void* const* d_in, const int* in_sizes, int n_in,
                              void* d_out, int out_size, void* d_ws, size_t ws_size,
                              hipStream_t stream) {
    const float* X      = (const float*)d_in[0];
    const float* y_prev = (const float*)d_in[1];
    const float* W1     = (const float*)d_in[2];
    const float* W2     = (const float*)d_in[4];
    const float* W_fc   = (const float*)d_in[6];
    const float* b_fc   = (const float*)d_in[7];
    const float* W_ih   = (const float*)d_in[8];
    const float* W_hh   = (const float*)d_in[9];
    const float* b_ih   = (const float*)d_in[10];
    const float* b_hh   = (const float*)d_in[11];
    const float* W_fin  = (const float*)d_in[12];
    const float* b_fin  = (const float*)d_in[13];
    char* ws = (char*)d_ws;

    hipLaunchKernelGGL(k_prep, dim3(256), dim3(256), 0, stream, W1, W2, W_hh, ws);
    hipLaunchKernelGGL(k_attn, dim3(512), dim3(512), 0, stream,
                       X, y_prev, W_fc, b_fc, W_fin, b_fin, (float*)d_out, ws);
    hipLaunchKernelGGL(k_lstm, dim3(256), dim3(256), 0, stream,
                       W_ih, b_ih, b_hh, W_fin, (float*)d_out, ws);
}

// Round 10
// 542.498 us; speedup vs baseline: 1.9128x; 1.0057x over previous
//
#include <hip/hip_runtime.h>
#include <stdint.h>

typedef __attribute__((ext_vector_type(8))) short short8;
typedef __attribute__((ext_vector_type(8))) unsigned short ushort8_t;
typedef __attribute__((ext_vector_type(4))) float floatx4;

#define T1 127
#define ENC 256
#define HD 256

// workspace offsets (bytes)
#define WHI_OFF   0u            // 1024*256 ushort = 524288
#define WLO_OFF   524288u
#define D0_OFF    1048576u      // 512*128 u64 = 524288  (epoch-tagged d words)
#define D1_OFF    1572864u
#define YT_OFF    2099200u      // 512*128 fp32 = 262144

__device__ __forceinline__ void split_bf16(float x, unsigned& hi, unsigned& lo) {
    unsigned u = __float_as_uint(x);
    hi = u >> 16;
    float hf = __uint_as_float(hi << 16);
    float r = x - hf;
    unsigned ur = __float_as_uint(r);
    lo = (ur + 0x7fffu + ((ur >> 16) & 1u)) >> 16;
}

__device__ __forceinline__ float sigm_f(float x) { return 1.f / (1.f + __expf(-x)); }
__device__ __forceinline__ float tanh_f(float x) {
    x = fminf(9.f, fmaxf(-9.f, x));
    float e = __expf(2.f * x);
    return (e - 1.f) / (e + 1.f);
}

// One 64-B line sample, agent-coherent (sc0 sc1: bypass L1+L2, served at IC/HBM).
// All 8 u64 words of a thread's poll octet live in this single aligned line and
// are written by one producer wave; per-8B atomicity holds (8-B stores), epoch
// bits are validated per word.
__device__ __forceinline__ void load64_ag(const unsigned long long* p,
                                          uint4& a, uint4& b, uint4& c, uint4& d) {
    asm volatile("global_load_dwordx4 %0, %4, off sc0 sc1\n\t"
                 "global_load_dwordx4 %1, %4, off offset:16 sc0 sc1\n\t"
                 "global_load_dwordx4 %2, %4, off offset:32 sc0 sc1\n\t"
                 "global_load_dwordx4 %3, %4, off offset:48 sc0 sc1\n\t"
                 "s_waitcnt vmcnt(0)"
                 : "=v"(a), "=v"(b), "=v"(c), "=v"(d)
                 : "v"((unsigned long long)p)
                 : "memory");
}

// ---------------- k_attn: k_prep folded in + scores -> softmax -> y_tilde + out-seed ----------------
// R20: k_prep launch deleted. Its jobs distributed over k_attn's 512 blocks:
//   blocks 0..127  : W_hh hi/lo split (512 thr x 1 float4 each, same per-thread work)
//   blocks 128..191: D0 epoch-0 zeroing (64 x 512 uint4)
//   every block    : weff computed in-block (R18-proven bit-identical FMA order)
// Plus R19's ILP4 context pass and the out-seed (k_final's ctx half).
__global__ __launch_bounds__(512) void k_attn(const float* __restrict__ X,
                                              const float* __restrict__ y_prev,
                                              const float* __restrict__ W1,
                                              const float* __restrict__ W2,
                                              const float* __restrict__ W_hh,
                                              const float* __restrict__ W_fc,
                                              const float* __restrict__ b_fc,
                                              const float* __restrict__ W_final,
                                              const float* __restrict__ b_final,
                                              float* __restrict__ out,
                                              char* __restrict__ ws) {
    __shared__ float s_lds[128];
    __shared__ float beta[128];
    __shared__ float part[512];
    __shared__ float wsum[8];
    __shared__ float fsum[8];
    __shared__ float su;
    const int b = blockIdx.x, tid = threadIdx.x;
    const int w = tid >> 6, lane = tid & 63;

    // ---- staged k_prep work (issued first; overlaps the attention phase) ----
    if (b < 128) {
        ushort* Whi = (ushort*)(ws + WHI_OFF);
        ushort* Wlo = (ushort*)(ws + WLO_OFF);
        const int i4 = b * 512 + tid;   // 0..65535
        float4 v = ((const float4*)W_hh)[i4];
        float vv[4] = {v.x, v.y, v.z, v.w};
        unsigned h[4], l[4];
        #pragma unroll
        for (int j = 0; j < 4; ++j) split_bf16(vv[j], h[j], l[j]);
        *(ushort4*)(Whi + i4 * 4) = make_ushort4((ushort)h[0], (ushort)h[1], (ushort)h[2], (ushort)h[3]);
        *(ushort4*)(Wlo + i4 * 4) = make_ushort4((ushort)l[0], (ushort)l[1], (ushort)l[2], (ushort)l[3]);
    } else if (b < 192) {
        const int idx = (b - 128) * 512 + tid;   // 0..32767
        ((uint4*)(ws + D0_OFF))[idx] = make_uint4(0, 0, 0, 0);
    }

    const float* Xb = X + (size_t)b * T1 * ENC;
    // weff components for this lane (k_prep's exact loop order -> same rounding)
    float4 w4; w4.x = w4.y = w4.z = w4.w = 0.f;
    {
        const float* W1c = W1 + 512 + lane * 4;
        #pragma unroll 4
        for (int j = 0; j < 128; ++j) {
            const float s = W2[j];
            const float4 c = *(const float4*)(W1c + j * 768);
            w4.x = fmaf(s, c.x, w4.x);
            w4.y = fmaf(s, c.y, w4.y);
            w4.z = fmaf(s, c.z, w4.z);
            w4.w = fmaf(s, c.w, w4.w);
        }
    }
    #pragma unroll 4
    for (int i = 0; i < 16; ++i) {
        int t = w * 16 + i;
        if (t >= T1) break;
        float4 x4 = ((const float4*)(Xb + t * ENC))[lane];
        float a = x4.x * w4.x + x4.y * w4.y + x4.z * w4.z + x4.w * w4.w;
        for (int m = 32; m >= 1; m >>= 1) a += __shfl_xor(a, m, 64);
        if (lane == 0) s_lds[t] = a;
    }
    __syncthreads();
    if (w == 0) {
        float v0 = s_lds[lane];
        float v1 = (lane + 64 < T1) ? s_lds[lane + 64] : -1e30f;
        float mx = fmaxf(v0, v1);
        for (int m = 32; m >= 1; m >>= 1) mx = fmaxf(mx, __shfl_xor(mx, m, 64));
        float e0 = __expf(v0 - mx);
        float e1 = (lane + 64 < T1) ? __expf(v1 - mx) : 0.f;
        float s = e0 + e1;
        for (int m = 32; m >= 1; m >>= 1) s += __shfl_xor(s, m, 64);
        float inv = 1.f / s;
        beta[lane] = e0 * inv;
        if (lane + 64 < T1) beta[lane + 64] = e1 * inv;
    }
    __syncthreads();
    {
        const int col = tid & 255, half = tid >> 8;
        const int t0 = half * 64;
        const int tend = half ? T1 : 64;
        float a0 = 0.f, a1 = 0.f, a2 = 0.f, a3 = 0.f;
        int t = t0;
        for (; t + 3 < tend; t += 4) {
            a0 = fmaf(beta[t],     Xb[t * ENC + col],       a0);
            a1 = fmaf(beta[t + 1], Xb[(t + 1) * ENC + col], a1);
            a2 = fmaf(beta[t + 2], Xb[(t + 2) * ENC + col], a2);
            a3 = fmaf(beta[t + 3], Xb[(t + 3) * ENC + col], a3);
        }
        for (; t < tend; ++t) a0 = fmaf(beta[t], Xb[t * ENC + col], a0);
        part[half * 256 + col] = (a0 + a1) + (a2 + a3);
    }
    __syncthreads();
    float v = 0.f, vf = 0.f;
    if (tid < 256) {
        float ctx = part[tid] + part[256 + tid];
        v  = ctx * W_fc[tid];
        vf = ctx * W_final[256 + tid];
    }
    for (int m = 32; m >= 1; m >>= 1) {
        v  += __shfl_xor(v, m, 64);
        vf += __shfl_xor(vf, m, 64);
    }
    if (lane == 0) { wsum[w] = v; fsum[w] = vf; }
    __syncthreads();
    if (tid == 0) {
        su = wsum[0] + wsum[1] + wsum[2] + wsum[3] + b_fc[0];
        out[b] = fsum[0] + fsum[1] + fsum[2] + fsum[3] + b_final[0];
    }
    __syncthreads();
    const float wy = W_fc[256];
    if (tid < T1)
        ((float*)(ws + YT_OFF))[b * 128 + tid] = su + wy * y_prev[b * T1 + tid];
}

// ---------------- k_lstm: persistent sequential LSTM, epoch-in-data exchange ----------------
// R10-proven topology, prologue, and t-loop (byte-identical: 256 blocks,
// gi = bid>>3, hj = bid&7, Whi/Wlo staged fragments, serial 64-B line poll,
// two __syncthreads, publish-first). R20 epilogue: at t = T1, block pre-reduces
// its 32 h-contributions per batch through gbuf (free after the cell phase),
// then issues ONE atomicAdd per batch (16 per block, 8-way contention across hj
// blocks — replaces R19's 128-way per-thread atomics whose RMW tail cost ~13 us).
__global__ __launch_bounds__(256, 1) void k_lstm(const float* __restrict__ W_ih,
                                                 const float* __restrict__ b_ih,
                                                 const float* __restrict__ b_hh,
                                                 const float* __restrict__ W_final,
                                                 float* __restrict__ out,
                                                 char* __restrict__ ws) {
    __shared__ __align__(16) ushort ldh[16 * 264];
    __shared__ __align__(16) ushort ldl[16 * 264];
    __shared__ float gbuf[16 * 132];

    const int tid = threadIdx.x, bid = blockIdx.x;
    const int gi = bid >> 3, hj = bid & 7;
    const int w = tid >> 6, lane = tid & 63;
    const int n16 = lane & 15, q = lane >> 4;

    const ushort* Whi = (const ushort*)(ws + WHI_OFF);
    const ushort* Wlo = (const ushort*)(ws + WLO_OFF);
    unsigned long long* Dbuf0 = (unsigned long long*)(ws + D0_OFF);
    unsigned long long* Dbuf1 = (unsigned long long*)(ws + D1_OFF);
    const float* yt = (const float*)(ws + YT_OFF);

    // resident W fragments: wave w owns N-tiles {2w, 2w+1}; row r = hloc*4 + g
    short8 bfh[2][8], bfl[2][8];
    #pragma unroll
    for (int j = 0; j < 2; ++j) {
        const int r = (2 * w + j) * 16 + n16;          // 0..127
        const int hloc = r >> 2, g = r & 3;
        const int R = g * 256 + hj * 32 + hloc;        // global gate row
        #pragma unroll
        for (int kt = 0; kt < 8; ++kt) {
            bfh[j][kt] = *(const short8*)(Whi + R * 256 + kt * 32 + q * 8);
            bfl[j][kt] = *(const short8*)(Wlo + R * 256 + kt * 32 + q * 8);
        }
    }

    // cell assignment: 16 batches x 32 h = 512 cells, 2 per thread
    const int b_loc = tid & 15, hpair = tid >> 4;      // hpair 0..15
    const int hloc0 = hpair * 2;
    const int bg = gi * 16 + b_loc;
    float wihr[2][4], bihr[2][4];
    #pragma unroll
    for (int jj = 0; jj < 2; ++jj)
        #pragma unroll
        for (int g = 0; g < 4; ++g) {
            const int row = g * HD + hj * 32 + hloc0 + jj;
            wihr[jj][g] = W_ih[row];
            bihr[jj][g] = b_ih[row] + b_hh[row];
        }
    float cc0 = 0.f, cc1 = 0.f;

    // poll/stage assignment: thread covers batch pb = tid>>4, hp8 = tid&15
    // words k = hp8*8 .. hp8*8+7 (cells h = 2k, 2k+1); origin block = hp8>>1
    const int pb = tid >> 4, hp8 = tid & 15;
    const bool own = ((hp8 >> 1) == hj);
    const size_t pbase = (size_t)(gi * 16 + pb) * 128 + hp8 * 8;   // 64B-aligned line

    // pre-zero this thread's full 16-ushort slab segment (d0 = 0) in BOTH planes
    {
        ushort8_t z = {0, 0, 0, 0, 0, 0, 0, 0};
        *(ushort8_t*)(ldh + pb * 264 + hp8 * 16)     = z;
        *(ushort8_t*)(ldh + pb * 264 + hp8 * 16 + 8) = z;
        *(ushort8_t*)(ldl + pb * 264 + hp8 * 16)     = z;
        *(ushort8_t*)(ldl + pb * 264 + hp8 * 16 + 8) = z;
    }

    for (int t = 1; t <= T1; ++t) {
        const float ytv = yt[bg * 128 + (t - 1)];   // prefetch, independent of d
        // ---- poll d_{t-1}: one 64-B line sample per round ----
        if (!own) {
            unsigned long long* Dsrc = ((t - 1) & 1) ? Dbuf1 : Dbuf0;
            const unsigned e = (unsigned)(t - 1) & 3u;
            unsigned lo[8], hi[8];
            for (int round = 0; ; ++round) {
                uint4 A, B, C, D;
                load64_ag(&Dsrc[pbase], A, B, C, D);
                lo[0] = A.x; hi[0] = A.y; lo[1] = A.z; hi[1] = A.w;
                lo[2] = B.x; hi[2] = B.y; lo[3] = B.z; hi[3] = B.w;
                lo[4] = C.x; hi[4] = C.y; lo[5] = C.z; hi[5] = C.w;
                lo[6] = D.x; hi[6] = D.y; lo[7] = D.z; hi[7] = D.w;
                bool ok = true;
                #pragma unroll
                for (int i = 0; i < 8; ++i) {
                    unsigned ep = (lo[i] & 1u) | ((hi[i] & 1u) << 1);
                    ok &= (ep == e);
                }
                if (ok) break;
                if (round >= 16) __builtin_amdgcn_s_sleep(1);
            }
            // decode: 16 hi + 16 lo ushorts -> two b128 stores per plane
            ushort hv[16], lv[16];
            #pragma unroll
            for (int i = 0; i < 8; ++i) {
                hv[2 * i]     = (ushort)(lo[i] >> 16);
                hv[2 * i + 1] = (ushort)(hi[i] >> 16);
                lv[2 * i]     = (ushort)(lo[i] & 0xFFFEu);
                lv[2 * i + 1] = (ushort)(hi[i] & 0xFFFEu);
            }
            ushort8_t H0, L0, H1, L1;
            #pragma unroll
            for (int i = 0; i < 8; ++i) { H0[i] = hv[i]; L0[i] = lv[i]; H1[i] = hv[8 + i]; L1[i] = lv[8 + i]; }
            *(ushort8_t*)(ldh + pb * 264 + hp8 * 16)     = H0;
            *(ushort8_t*)(ldh + pb * 264 + hp8 * 16 + 8) = H1;
            *(ushort8_t*)(ldl + pb * 264 + hp8 * 16)     = L0;
            *(ushort8_t*)(ldl + pb * 264 + hp8 * 16 + 8) = L1;
        }
        __syncthreads();
        // MFMA: gates[16b x 128r] = d[16x256] @ Wslice^T  (hi*hi + lo*hi + hi*lo)
        floatx4 acc0 = {0.f, 0.f, 0.f, 0.f}, acc1 = {0.f, 0.f, 0.f, 0.f};
        #pragma unroll
        for (int kt = 0; kt < 8; ++kt) {
            short8 ah = *(const short8*)(ldh + n16 * 264 + kt * 32 + q * 8);
            short8 al = *(const short8*)(ldl + n16 * 264 + kt * 32 + q * 8);
            acc0 = __builtin_amdgcn_mfma_f32_16x16x32_bf16(ah, bfh[0][kt], acc0, 0, 0, 0);
            acc0 = __builtin_amdgcn_mfma_f32_16x16x32_bf16(al, bfh[0][kt], acc0, 0, 0, 0);
            acc0 = __builtin_amdgcn_mfma_f32_16x16x32_bf16(ah, bfl[0][kt], acc0, 0, 0, 0);
            acc1 = __builtin_amdgcn_mfma_f32_16x16x32_bf16(ah, bfh[1][kt], acc1, 0, 0, 0);
            acc1 = __builtin_amdgcn_mfma_f32_16x16x32_bf16(al, bfh[1][kt], acc1, 0, 0, 0);
            acc1 = __builtin_amdgcn_mfma_f32_16x16x32_bf16(ah, bfl[1][kt], acc1, 0, 0, 0);
        }
        // scatter C-frags: row m = q*4+reg (batch), col = tile*16+n16 (gate row)
        #pragma unroll
        for (int reg = 0; reg < 4; ++reg) {
            gbuf[(q * 4 + reg) * 132 + (2 * w) * 16 + n16]     = acc0[reg];
            gbuf[(q * 4 + reg) * 132 + (2 * w + 1) * 16 + n16] = acc1[reg];
        }
        __syncthreads();
        // LSTM cell: 2 cells per thread
        float dnew[2];
        #pragma unroll
        for (int jj = 0; jj < 2; ++jj) {
            const int base = b_loc * 132 + (hloc0 + jj) * 4;
            float pi = gbuf[base + 0] + ytv * wihr[jj][0] + bihr[jj][0];
            float pf = gbuf[base + 1] + ytv * wihr[jj][1] + bihr[jj][1];
            float pg = gbuf[base + 2] + ytv * wihr[jj][2] + bihr[jj][2];
            float po = gbuf[base + 3] + ytv * wihr[jj][3] + bihr[jj][3];
            float ig = sigm_f(pi), fg = sigm_f(pf), og = sigm_f(po);
            float gg = tanh_f(pg);
            float& c = jj ? cc1 : cc0;
            c = fg * c + ig * gg;
            dnew[jj] = og * tanh_f(c);
        }
        if (t < T1) {
            const unsigned e = (unsigned)t & 3u;
            unsigned h0, l0, h1, l1;
            split_bf16(dnew[0], h0, l0);
            split_bf16(dnew[1], h1, l1);
            l0 = (l0 & 0xFFFEu) | (e & 1u);
            l1 = (l1 & 0xFFFEu) | ((e >> 1) & 1u);
            // publish FIRST (earliest visibility for the 7 consumer blocks)
            unsigned long long wv = ((unsigned long long)h1 << 48) |
                                    ((unsigned long long)l1 << 32) |
                                    ((unsigned long long)h0 << 16) |
                                    (unsigned long long)l0;
            unsigned long long* Ddst = (t & 1) ? Dbuf1 : Dbuf0;
            __hip_atomic_store(&Ddst[(size_t)bg * 128 + hj * 16 + hpair], wv,
                               __ATOMIC_RELAXED, __HIP_MEMORY_SCOPE_AGENT);
            // own slice -> directly into next step's LDS slab (barrier-ordered)
            *(ushort2*)(ldh + b_loc * 264 + hj * 32 + hloc0) =
                make_ushort2((ushort)h0, (ushort)h1);
            *(ushort2*)(ldl + b_loc * 264 + hj * 32 + hloc0) =
                make_ushort2((ushort)(l0 & 0xFFFEu), (ushort)(l1 & 0xFFFEu));
        } else {
            // fused k_final (dT half) with LDS pre-reduction: ONE atomicAdd per
            // batch per block (8-way contention across hj blocks).
            const float wf0 = W_final[hj * 32 + hloc0];
            const float wf1 = W_final[hj * 32 + hloc0 + 1];
            __syncthreads();   // all cell-phase gbuf reads complete (uniform branch)
            gbuf[hpair * 16 + b_loc] = dnew[0] * wf0 + dnew[1] * wf1;
            __syncthreads();
            if (tid < 16) {
                float s = 0.f;
                #pragma unroll
                for (int h = 0; h < 16; ++h) s += gbuf[h * 16 + tid];
                atomicAdd(out + gi * 16 + tid, s);
            }
        }
    }
}

extern "C" void kernel_launch(void* const* d_in, const int* in_sizes, int n_in,
                              void* d_out, int out_size, void* d_ws, size_t ws_size,
                              hipStream_t stream) {
    const float* X      = (const float*)d_in[0];
    const float* y_prev = (const float*)d_in[1];
    const float* W1     = (const float*)d_in[2];
    const float* W2     = (const float*)d_in[4];
    const float* W_fc   = (const float*)d_in[6];
    const float* b_fc   = (const float*)d_in[7];
    const float* W_ih   = (const float*)d_in[8];
    const float* W_hh   = (const float*)d_in[9];
    const float* b_ih   = (const float*)d_in[10];
    const float* b_hh   = (const float*)d_in[11];
    const float* W_fin  = (const float*)d_in[12];
    const float* b_fin  = (const float*)d_in[13];
    char* ws = (char*)d_ws;

    hipLaunchKernelGGL(k_attn, dim3(512), dim3(512), 0, stream,
                       X, y_prev, W1, W2, W_hh, W_fc, b_fc, W_fin, b_fin,
                       (float*)d_out, ws);
    hipLaunchKernelGGL(k_lstm, dim3(256), dim3(256), 0, stream,
                       W_ih, b_ih, b_hh, W_fin, (float*)d_out, ws);
}

// Round 11
// 539.629 us; speedup vs baseline: 1.9230x; 1.0053x over previous
//
#include <hip/hip_runtime.h>
#include <stdint.h>

typedef __attribute__((ext_vector_type(8))) short short8;
typedef __attribute__((ext_vector_type(8))) unsigned short ushort8_t;
typedef __attribute__((ext_vector_type(4))) float floatx4;

#define T1 127
#define ENC 256
#define HD 256

// workspace offsets (bytes)
#define WHI_OFF   0u            // 1024*256 ushort = 524288
#define WLO_OFF   524288u
#define D0_OFF    1048576u      // 512*128 u64 = 524288  (epoch-tagged d words)
#define D1_OFF    1572864u
#define YT_OFF    2099200u      // 512*128 fp32 = 262144

__device__ __forceinline__ void split_bf16(float x, unsigned& hi, unsigned& lo) {
    unsigned u = __float_as_uint(x);
    hi = u >> 16;
    float hf = __uint_as_float(hi << 16);
    float r = x - hf;
    unsigned ur = __float_as_uint(r);
    lo = (ur + 0x7fffu + ((ur >> 16) & 1u)) >> 16;
}

__device__ __forceinline__ float sigm_f(float x) { return 1.f / (1.f + __expf(-x)); }
__device__ __forceinline__ float tanh_f(float x) {
    x = fminf(9.f, fmaxf(-9.f, x));
    float e = __expf(2.f * x);
    return (e - 1.f) / (e + 1.f);
}

// One 64-B line sample, agent-coherent (sc0 sc1: bypass L1+L2, served at IC/HBM).
// All 8 u64 words of a thread's poll octet live in this single aligned line and
// are written by one producer wave; per-8B atomicity holds (8-B stores), epoch
// bits are validated per word.
__device__ __forceinline__ void load64_ag(const unsigned long long* p,
                                          uint4& a, uint4& b, uint4& c, uint4& d) {
    asm volatile("global_load_dwordx4 %0, %4, off sc0 sc1\n\t"
                 "global_load_dwordx4 %1, %4, off offset:16 sc0 sc1\n\t"
                 "global_load_dwordx4 %2, %4, off offset:32 sc0 sc1\n\t"
                 "global_load_dwordx4 %3, %4, off offset:48 sc0 sc1\n\t"
                 "s_waitcnt vmcnt(0)"
                 : "=v"(a), "=v"(b), "=v"(c), "=v"(d)
                 : "v"((unsigned long long)p)
                 : "memory");
}

// ---------------- k_attn: k_prep folded in + scores -> softmax -> y_tilde + out-seed ----------------
// R21: pass 1 now processes TWO rows per iteration (t and t+8) with interleaved
// independent shuffle chains — 2x loads in flight, dual-issued reduce. Per-row
// summation order unchanged (bit-exact). Everything else R20-proven:
//   blocks 0..127  : W_hh hi/lo split   blocks 128..191: D0 epoch-0 zeroing
//   every block    : weff in-block (k_prep's exact FMA order)
//   pass 3 ILP4 context; out[b] seeded with W_final[256:]·ctx + b_final.
__global__ __launch_bounds__(512) void k_attn(const float* __restrict__ X,
                                              const float* __restrict__ y_prev,
                                              const float* __restrict__ W1,
                                              const float* __restrict__ W2,
                                              const float* __restrict__ W_hh,
                                              const float* __restrict__ W_fc,
                                              const float* __restrict__ b_fc,
                                              const float* __restrict__ W_final,
                                              const float* __restrict__ b_final,
                                              float* __restrict__ out,
                                              char* __restrict__ ws) {
    __shared__ float s_lds[128];
    __shared__ float beta[128];
    __shared__ float part[512];
    __shared__ float wsum[8];
    __shared__ float fsum[8];
    __shared__ float su;
    const int b = blockIdx.x, tid = threadIdx.x;
    const int w = tid >> 6, lane = tid & 63;

    // ---- staged k_prep work (issued first; overlaps the attention phase) ----
    if (b < 128) {
        ushort* Whi = (ushort*)(ws + WHI_OFF);
        ushort* Wlo = (ushort*)(ws + WLO_OFF);
        const int i4 = b * 512 + tid;   // 0..65535
        float4 v = ((const float4*)W_hh)[i4];
        float vv[4] = {v.x, v.y, v.z, v.w};
        unsigned h[4], l[4];
        #pragma unroll
        for (int j = 0; j < 4; ++j) split_bf16(vv[j], h[j], l[j]);
        *(ushort4*)(Whi + i4 * 4) = make_ushort4((ushort)h[0], (ushort)h[1], (ushort)h[2], (ushort)h[3]);
        *(ushort4*)(Wlo + i4 * 4) = make_ushort4((ushort)l[0], (ushort)l[1], (ushort)l[2], (ushort)l[3]);
    } else if (b < 192) {
        const int idx = (b - 128) * 512 + tid;   // 0..32767
        ((uint4*)(ws + D0_OFF))[idx] = make_uint4(0, 0, 0, 0);
    }

    const float* Xb = X + (size_t)b * T1 * ENC;
    // weff components for this lane (k_prep's exact loop order -> same rounding)
    float4 w4; w4.x = w4.y = w4.z = w4.w = 0.f;
    {
        const float* W1c = W1 + 512 + lane * 4;
        #pragma unroll 4
        for (int j = 0; j < 128; ++j) {
            const float s = W2[j];
            const float4 c = *(const float4*)(W1c + j * 768);
            w4.x = fmaf(s, c.x, w4.x);
            w4.y = fmaf(s, c.y, w4.y);
            w4.z = fmaf(s, c.z, w4.z);
            w4.w = fmaf(s, c.w, w4.w);
        }
    }
    // pass 1: scores, 2-row interleave (t and t+8), per-row order unchanged
    #pragma unroll
    for (int i = 0; i < 8; ++i) {
        const int t0 = w * 16 + i;
        const int t1 = t0 + 8;
        const bool ok0 = (t0 < T1), ok1 = (t1 < T1);
        float a0 = 0.f, a1 = 0.f;
        if (ok0) {
            float4 x4 = ((const float4*)(Xb + t0 * ENC))[lane];
            a0 = x4.x * w4.x + x4.y * w4.y + x4.z * w4.z + x4.w * w4.w;
        }
        if (ok1) {
            float4 x4 = ((const float4*)(Xb + t1 * ENC))[lane];
            a1 = x4.x * w4.x + x4.y * w4.y + x4.z * w4.z + x4.w * w4.w;
        }
        #pragma unroll
        for (int m = 32; m >= 1; m >>= 1) {
            a0 += __shfl_xor(a0, m, 64);
            a1 += __shfl_xor(a1, m, 64);
        }
        if (lane == 0) {
            if (ok0) s_lds[t0] = a0;
            if (ok1) s_lds[t1] = a1;
        }
    }
    __syncthreads();
    if (w == 0) {
        float v0 = s_lds[lane];
        float v1 = (lane + 64 < T1) ? s_lds[lane + 64] : -1e30f;
        float mx = fmaxf(v0, v1);
        for (int m = 32; m >= 1; m >>= 1) mx = fmaxf(mx, __shfl_xor(mx, m, 64));
        float e0 = __expf(v0 - mx);
        float e1 = (lane + 64 < T1) ? __expf(v1 - mx) : 0.f;
        float s = e0 + e1;
        for (int m = 32; m >= 1; m >>= 1) s += __shfl_xor(s, m, 64);
        float inv = 1.f / s;
        beta[lane] = e0 * inv;
        if (lane + 64 < T1) beta[lane + 64] = e1 * inv;
    }
    __syncthreads();
    {
        const int col = tid & 255, half = tid >> 8;
        const int t0 = half * 64;
        const int tend = half ? T1 : 64;
        float a0 = 0.f, a1 = 0.f, a2 = 0.f, a3 = 0.f;
        int t = t0;
        for (; t + 3 < tend; t += 4) {
            a0 = fmaf(beta[t],     Xb[t * ENC + col],       a0);
            a1 = fmaf(beta[t + 1], Xb[(t + 1) * ENC + col], a1);
            a2 = fmaf(beta[t + 2], Xb[(t + 2) * ENC + col], a2);
            a3 = fmaf(beta[t + 3], Xb[(t + 3) * ENC + col], a3);
        }
        for (; t < tend; ++t) a0 = fmaf(beta[t], Xb[t * ENC + col], a0);
        part[half * 256 + col] = (a0 + a1) + (a2 + a3);
    }
    __syncthreads();
    float v = 0.f, vf = 0.f;
    if (tid < 256) {
        float ctx = part[tid] + part[256 + tid];
        v  = ctx * W_fc[tid];
        vf = ctx * W_final[256 + tid];
    }
    for (int m = 32; m >= 1; m >>= 1) {
        v  += __shfl_xor(v, m, 64);
        vf += __shfl_xor(vf, m, 64);
    }
    if (lane == 0) { wsum[w] = v; fsum[w] = vf; }
    __syncthreads();
    if (tid == 0) {
        su = wsum[0] + wsum[1] + wsum[2] + wsum[3] + b_fc[0];
        out[b] = fsum[0] + fsum[1] + fsum[2] + fsum[3] + b_final[0];
    }
    __syncthreads();
    const float wy = W_fc[256];
    if (tid < T1)
        ((float*)(ws + YT_OFF))[b * 128 + tid] = su + wy * y_prev[b * T1 + tid];
}

// ---------------- k_lstm: persistent sequential LSTM, epoch-in-data exchange ----------------
// R20-proven, byte-identical: R10 topology/prologue/t-loop (256 blocks,
// gi = bid>>3, hj = bid&7, Whi/Wlo staged fragments, serial 64-B line poll,
// two __syncthreads, publish-first) + t = T1 epilogue with LDS pre-reduction and
// ONE atomicAdd per batch per block (8-way contention).
__global__ __launch_bounds__(256, 1) void k_lstm(const float* __restrict__ W_ih,
                                                 const float* __restrict__ b_ih,
                                                 const float* __restrict__ b_hh,
                                                 const float* __restrict__ W_final,
                                                 float* __restrict__ out,
                                                 char* __restrict__ ws) {
    __shared__ __align__(16) ushort ldh[16 * 264];
    __shared__ __align__(16) ushort ldl[16 * 264];
    __shared__ float gbuf[16 * 132];

    const int tid = threadIdx.x, bid = blockIdx.x;
    const int gi = bid >> 3, hj = bid & 7;
    const int w = tid >> 6, lane = tid & 63;
    const int n16 = lane & 15, q = lane >> 4;

    const ushort* Whi = (const ushort*)(ws + WHI_OFF);
    const ushort* Wlo = (const ushort*)(ws + WLO_OFF);
    unsigned long long* Dbuf0 = (unsigned long long*)(ws + D0_OFF);
    unsigned long long* Dbuf1 = (unsigned long long*)(ws + D1_OFF);
    const float* yt = (const float*)(ws + YT_OFF);

    // resident W fragments: wave w owns N-tiles {2w, 2w+1}; row r = hloc*4 + g
    short8 bfh[2][8], bfl[2][8];
    #pragma unroll
    for (int j = 0; j < 2; ++j) {
        const int r = (2 * w + j) * 16 + n16;          // 0..127
        const int hloc = r >> 2, g = r & 3;
        const int R = g * 256 + hj * 32 + hloc;        // global gate row
        #pragma unroll
        for (int kt = 0; kt < 8; ++kt) {
            bfh[j][kt] = *(const short8*)(Whi + R * 256 + kt * 32 + q * 8);
            bfl[j][kt] = *(const short8*)(Wlo + R * 256 + kt * 32 + q * 8);
        }
    }

    // cell assignment: 16 batches x 32 h = 512 cells, 2 per thread
    const int b_loc = tid & 15, hpair = tid >> 4;      // hpair 0..15
    const int hloc0 = hpair * 2;
    const int bg = gi * 16 + b_loc;
    float wihr[2][4], bihr[2][4];
    #pragma unroll
    for (int jj = 0; jj < 2; ++jj)
        #pragma unroll
        for (int g = 0; g < 4; ++g) {
            const int row = g * HD + hj * 32 + hloc0 + jj;
            wihr[jj][g] = W_ih[row];
            bihr[jj][g] = b_ih[row] + b_hh[row];
        }
    float cc0 = 0.f, cc1 = 0.f;

    // poll/stage assignment: thread covers batch pb = tid>>4, hp8 = tid&15
    // words k = hp8*8 .. hp8*8+7 (cells h = 2k, 2k+1); origin block = hp8>>1
    const int pb = tid >> 4, hp8 = tid & 15;
    const bool own = ((hp8 >> 1) == hj);
    const size_t pbase = (size_t)(gi * 16 + pb) * 128 + hp8 * 8;   // 64B-aligned line

    // pre-zero this thread's full 16-ushort slab segment (d0 = 0) in BOTH planes
    {
        ushort8_t z = {0, 0, 0, 0, 0, 0, 0, 0};
        *(ushort8_t*)(ldh + pb * 264 + hp8 * 16)     = z;
        *(ushort8_t*)(ldh + pb * 264 + hp8 * 16 + 8) = z;
        *(ushort8_t*)(ldl + pb * 264 + hp8 * 16)     = z;
        *(ushort8_t*)(ldl + pb * 264 + hp8 * 16 + 8) = z;
    }

    for (int t = 1; t <= T1; ++t) {
        const float ytv = yt[bg * 128 + (t - 1)];   // prefetch, independent of d
        // ---- poll d_{t-1}: one 64-B line sample per round ----
        if (!own) {
            unsigned long long* Dsrc = ((t - 1) & 1) ? Dbuf1 : Dbuf0;
            const unsigned e = (unsigned)(t - 1) & 3u;
            unsigned lo[8], hi[8];
            for (int round = 0; ; ++round) {
                uint4 A, B, C, D;
                load64_ag(&Dsrc[pbase], A, B, C, D);
                lo[0] = A.x; hi[0] = A.y; lo[1] = A.z; hi[1] = A.w;
                lo[2] = B.x; hi[2] = B.y; lo[3] = B.z; hi[3] = B.w;
                lo[4] = C.x; hi[4] = C.y; lo[5] = C.z; hi[5] = C.w;
                lo[6] = D.x; hi[6] = D.y; lo[7] = D.z; hi[7] = D.w;
                bool ok = true;
                #pragma unroll
                for (int i = 0; i < 8; ++i) {
                    unsigned ep = (lo[i] & 1u) | ((hi[i] & 1u) << 1);
                    ok &= (ep == e);
                }
                if (ok) break;
                if (round >= 16) __builtin_amdgcn_s_sleep(1);
            }
            // decode: 16 hi + 16 lo ushorts -> two b128 stores per plane
            ushort hv[16], lv[16];
            #pragma unroll
            for (int i = 0; i < 8; ++i) {
                hv[2 * i]     = (ushort)(lo[i] >> 16);
                hv[2 * i + 1] = (ushort)(hi[i] >> 16);
                lv[2 * i]     = (ushort)(lo[i] & 0xFFFEu);
                lv[2 * i + 1] = (ushort)(hi[i] & 0xFFFEu);
            }
            ushort8_t H0, L0, H1, L1;
            #pragma unroll
            for (int i = 0; i < 8; ++i) { H0[i] = hv[i]; L0[i] = lv[i]; H1[i] = hv[8 + i]; L1[i] = lv[8 + i]; }
            *(ushort8_t*)(ldh + pb * 264 + hp8 * 16)     = H0;
            *(ushort8_t*)(ldh + pb * 264 + hp8 * 16 + 8) = H1;
            *(ushort8_t*)(ldl + pb * 264 + hp8 * 16)     = L0;
            *(ushort8_t*)(ldl + pb * 264 + hp8 * 16 + 8) = L1;
        }
        __syncthreads();
        // MFMA: gates[16b x 128r] = d[16x256] @ Wslice^T  (hi*hi + lo*hi + hi*lo)
        floatx4 acc0 = {0.f, 0.f, 0.f, 0.f}, acc1 = {0.f, 0.f, 0.f, 0.f};
        #pragma unroll
        for (int kt = 0; kt < 8; ++kt) {
            short8 ah = *(const short8*)(ldh + n16 * 264 + kt * 32 + q * 8);
            short8 al = *(const short8*)(ldl + n16 * 264 + kt * 32 + q * 8);
            acc0 = __builtin_amdgcn_mfma_f32_16x16x32_bf16(ah, bfh[0][kt], acc0, 0, 0, 0);
            acc0 = __builtin_amdgcn_mfma_f32_16x16x32_bf16(al, bfh[0][kt], acc0, 0, 0, 0);
            acc0 = __builtin_amdgcn_mfma_f32_16x16x32_bf16(ah, bfl[0][kt], acc0, 0, 0, 0);
            acc1 = __builtin_amdgcn_mfma_f32_16x16x32_bf16(ah, bfh[1][kt], acc1, 0, 0, 0);
            acc1 = __builtin_amdgcn_mfma_f32_16x16x32_bf16(al, bfh[1][kt], acc1, 0, 0, 0);
            acc1 = __builtin_amdgcn_mfma_f32_16x16x32_bf16(ah, bfl[1][kt], acc1, 0, 0, 0);
        }
        // scatter C-frags: row m = q*4+reg (batch), col = tile*16+n16 (gate row)
        #pragma unroll
        for (int reg = 0; reg < 4; ++reg) {
            gbuf[(q * 4 + reg) * 132 + (2 * w) * 16 + n16]     = acc0[reg];
            gbuf[(q * 4 + reg) * 132 + (2 * w + 1) * 16 + n16] = acc1[reg];
        }
        __syncthreads();
        // LSTM cell: 2 cells per thread
        float dnew[2];
        #pragma unroll
        for (int jj = 0; jj < 2; ++jj) {
            const int base = b_loc * 132 + (hloc0 + jj) * 4;
            float pi = gbuf[base + 0] + ytv * wihr[jj][0] + bihr[jj][0];
            float pf = gbuf[base + 1] + ytv * wihr[jj][1] + bihr[jj][1];
            float pg = gbuf[base + 2] + ytv * wihr[jj][2] + bihr[jj][2];
            float po = gbuf[base + 3] + ytv * wihr[jj][3] + bihr[jj][3];
            float ig = sigm_f(pi), fg = sigm_f(pf), og = sigm_f(po);
            float gg = tanh_f(pg);
            float& c = jj ? cc1 : cc0;
            c = fg * c + ig * gg;
            dnew[jj] = og * tanh_f(c);
        }
        if (t < T1) {
            const unsigned e = (unsigned)t & 3u;
            unsigned h0, l0, h1, l1;
            split_bf16(dnew[0], h0, l0);
            split_bf16(dnew[1], h1, l1);
            l0 = (l0 & 0xFFFEu) | (e & 1u);
            l1 = (l1 & 0xFFFEu) | ((e >> 1) & 1u);
            // publish FIRST (earliest visibility for the 7 consumer blocks)
            unsigned long long wv = ((unsigned long long)h1 << 48) |
                                    ((unsigned long long)l1 << 32) |
                                    ((unsigned long long)h0 << 16) |
                                    (unsigned long long)l0;
            unsigned long long* Ddst = (t & 1) ? Dbuf1 : Dbuf0;
            __hip_atomic_store(&Ddst[(size_t)bg * 128 + hj * 16 + hpair], wv,
                               __ATOMIC_RELAXED, __HIP_MEMORY_SCOPE_AGENT);
            // own slice -> directly into next step's LDS slab (barrier-ordered)
            *(ushort2*)(ldh + b_loc * 264 + hj * 32 + hloc0) =
                make_ushort2((ushort)h0, (ushort)h1);
            *(ushort2*)(ldl + b_loc * 264 + hj * 32 + hloc0) =
                make_ushort2((ushort)(l0 & 0xFFFEu), (ushort)(l1 & 0xFFFEu));
        } else {
            // fused k_final (dT half) with LDS pre-reduction: ONE atomicAdd per
            // batch per block (8-way contention across hj blocks).
            const float wf0 = W_final[hj * 32 + hloc0];
            const float wf1 = W_final[hj * 32 + hloc0 + 1];
            __syncthreads();   // all cell-phase gbuf reads complete (uniform branch)
            gbuf[hpair * 16 + b_loc] = dnew[0] * wf0 + dnew[1] * wf1;
            __syncthreads();
            if (tid < 16) {
                float s = 0.f;
                #pragma unroll
                for (int h = 0; h < 16; ++h) s += gbuf[h * 16 + tid];
                atomicAdd(out + gi * 16 + tid, s);
            }
        }
    }
}

extern "C" void kernel_launch(void* const* d_in, const int* in_sizes, int n_in,
                              void* d_out, int out_size, void* d_ws, size_t ws_size,
                              hipStream_t stream) {
    const float* X      = (const float*)d_in[0];
    const float* y_prev = (const float*)d_in[1];
    const float* W1     = (const float*)d_in[2];
    const float* W2     = (const float*)d_in[4];
    const float* W_fc   = (const float*)d_in[6];
    const float* b_fc   = (const float*)d_in[7];
    const float* W_ih   = (const float*)d_in[8];
    const float* W_hh   = (const float*)d_in[9];
    const float* b_ih   = (const float*)d_in[10];
    const float* b_hh   = (const float*)d_in[11];
    const float* W_fin  = (const float*)d_in[12];
    const float* b_fin  = (const float*)d_in[13];
    char* ws = (char*)d_ws;

    hipLaunchKernelGGL(k_attn, dim3(512), dim3(512), 0, stream,
                       X, y_prev, W1, W2, W_hh, W_fc, b_fc, W_fin, b_fin,
                       (float*)d_out, ws);
    hipLaunchKernelGGL(k_lstm, dim3(256), dim3(256), 0, stream,
                       W_ih, b_ih, b_hh, W_fin, (float*)d_out, ws);
}

// Round 12
// 533.659 us; speedup vs baseline: 1.9445x; 1.0112x over previous
//
#include <hip/hip_runtime.h>
#include <stdint.h>

typedef __attribute__((ext_vector_type(8))) short short8;
typedef __attribute__((ext_vector_type(8))) unsigned short ushort8_t;
typedef __attribute__((ext_vector_type(4))) float floatx4;

#define T1 127
#define ENC 256
#define HD 256

// workspace offsets (bytes)
#define WHI_OFF   0u            // 1024*256 ushort = 524288
#define WLO_OFF   524288u
#define D0_OFF    1048576u      // 512*128 u64 = 524288  (epoch-tagged d words)
#define D1_OFF    1572864u
#define YT_OFF    2099200u      // 512*128 fp32 = 262144

__device__ __forceinline__ void split_bf16(float x, unsigned& hi, unsigned& lo) {
    unsigned u = __float_as_uint(x);
    hi = u >> 16;
    float hf = __uint_as_float(hi << 16);
    float r = x - hf;
    unsigned ur = __float_as_uint(r);
    lo = (ur + 0x7fffu + ((ur >> 16) & 1u)) >> 16;
}

__device__ __forceinline__ float sigm_f(float x) { return 1.f / (1.f + __expf(-x)); }
__device__ __forceinline__ float tanh_f(float x) {
    x = fminf(9.f, fmaxf(-9.f, x));
    float e = __expf(2.f * x);
    return (e - 1.f) / (e + 1.f);
}

// One 64-B line sample, agent-coherent (sc0 sc1: bypass L1+L2, served at IC/HBM).
// All 8 u64 words of a thread's poll octet live in this single aligned line and
// are written by one producer wave; per-8B atomicity holds (8-B stores), epoch
// bits are validated per word.
__device__ __forceinline__ void load64_ag(const unsigned long long* p,
                                          uint4& a, uint4& b, uint4& c, uint4& d) {
    asm volatile("global_load_dwordx4 %0, %4, off sc0 sc1\n\t"
                 "global_load_dwordx4 %1, %4, off offset:16 sc0 sc1\n\t"
                 "global_load_dwordx4 %2, %4, off offset:32 sc0 sc1\n\t"
                 "global_load_dwordx4 %3, %4, off offset:48 sc0 sc1\n\t"
                 "s_waitcnt vmcnt(0)"
                 : "=v"(a), "=v"(b), "=v"(c), "=v"(d)
                 : "v"((unsigned long long)p)
                 : "memory");
}

// ---------------- k_attn: single-X-pass attention + folded prep + out-seed ----------------
// R22: X is read ONCE. Pass 1 stashes each thread's 16 rows x float4 in registers
// (statically indexed); after softmax the context is a register-resident beta-
// weighted sum (beta via LDS broadcast), combined across the 8 waves through an
// 8 KB LDS tile. Deletes the second 66.5 MB X pass and its serial load chains.
// Unchanged (proven): weff in-block (k_prep's exact FMA order), 2-row-interleave
// score pass, folded W-split (blocks 0..127) and D0-zero (128..191), out-seed.
__global__ __launch_bounds__(512) void k_attn(const float* __restrict__ X,
                                              const float* __restrict__ y_prev,
                                              const float* __restrict__ W1,
                                              const float* __restrict__ W2,
                                              const float* __restrict__ W_hh,
                                              const float* __restrict__ W_fc,
                                              const float* __restrict__ b_fc,
                                              const float* __restrict__ W_final,
                                              const float* __restrict__ b_final,
                                              float* __restrict__ out,
                                              char* __restrict__ ws) {
    __shared__ float s_lds[128];
    __shared__ float beta[128];
    __shared__ float cpart[8][256];
    __shared__ float wsum[8];
    __shared__ float fsum[8];
    __shared__ float su;
    const int b = blockIdx.x, tid = threadIdx.x;
    const int w = tid >> 6, lane = tid & 63;

    // ---- staged k_prep work (issued first; overlaps the attention phase) ----
    if (b < 128) {
        ushort* Whi = (ushort*)(ws + WHI_OFF);
        ushort* Wlo = (ushort*)(ws + WLO_OFF);
        const int i4 = b * 512 + tid;   // 0..65535
        float4 v = ((const float4*)W_hh)[i4];
        float vv[4] = {v.x, v.y, v.z, v.w};
        unsigned h[4], l[4];
        #pragma unroll
        for (int j = 0; j < 4; ++j) split_bf16(vv[j], h[j], l[j]);
        *(ushort4*)(Whi + i4 * 4) = make_ushort4((ushort)h[0], (ushort)h[1], (ushort)h[2], (ushort)h[3]);
        *(ushort4*)(Wlo + i4 * 4) = make_ushort4((ushort)l[0], (ushort)l[1], (ushort)l[2], (ushort)l[3]);
    } else if (b < 192) {
        const int idx = (b - 128) * 512 + tid;   // 0..32767
        ((uint4*)(ws + D0_OFF))[idx] = make_uint4(0, 0, 0, 0);
    }

    const float* Xb = X + (size_t)b * T1 * ENC;
    // weff components for this lane (k_prep's exact loop order -> same rounding)
    float4 w4; w4.x = w4.y = w4.z = w4.w = 0.f;
    {
        const float* W1c = W1 + 512 + lane * 4;
        #pragma unroll 4
        for (int j = 0; j < 128; ++j) {
            const float s = W2[j];
            const float4 c = *(const float4*)(W1c + j * 768);
            w4.x = fmaf(s, c.x, w4.x);
            w4.y = fmaf(s, c.y, w4.y);
            w4.z = fmaf(s, c.z, w4.z);
            w4.w = fmaf(s, c.w, w4.w);
        }
    }
    // pass 1: scores with 2-row interleave; X rows stashed in registers
    float4 xr[16];
    #pragma unroll
    for (int i = 0; i < 8; ++i) {
        const int t0 = w * 16 + i;
        const int t1 = t0 + 8;
        const bool ok0 = (t0 < T1), ok1 = (t1 < T1);
        float a0 = 0.f, a1 = 0.f;
        if (ok0) {
            xr[i] = ((const float4*)(Xb + t0 * ENC))[lane];
            a0 = xr[i].x * w4.x + xr[i].y * w4.y + xr[i].z * w4.z + xr[i].w * w4.w;
        }
        if (ok1) {
            xr[i + 8] = ((const float4*)(Xb + t1 * ENC))[lane];
            a1 = xr[i + 8].x * w4.x + xr[i + 8].y * w4.y + xr[i + 8].z * w4.z + xr[i + 8].w * w4.w;
        }
        #pragma unroll
        for (int m = 32; m >= 1; m >>= 1) {
            a0 += __shfl_xor(a0, m, 64);
            a1 += __shfl_xor(a1, m, 64);
        }
        if (lane == 0) {
            if (ok0) s_lds[t0] = a0;
            if (ok1) s_lds[t1] = a1;
        }
    }
    __syncthreads();
    if (w == 0) {
        float v0 = s_lds[lane];
        float v1 = (lane + 64 < T1) ? s_lds[lane + 64] : -1e30f;
        float mx = fmaxf(v0, v1);
        for (int m = 32; m >= 1; m >>= 1) mx = fmaxf(mx, __shfl_xor(mx, m, 64));
        float e0 = __expf(v0 - mx);
        float e1 = (lane + 64 < T1) ? __expf(v1 - mx) : 0.f;
        float s = e0 + e1;
        for (int m = 32; m >= 1; m >>= 1) s += __shfl_xor(s, m, 64);
        float inv = 1.f / s;
        beta[lane] = e0 * inv;
        if (lane + 64 < T1) beta[lane + 64] = e1 * inv;
    }
    __syncthreads();
    // context from registers: per-thread beta-weighted sum over its 16 rows
    {
        float4 cp; cp.x = cp.y = cp.z = cp.w = 0.f;
        #pragma unroll
        for (int i = 0; i < 16; ++i) {
            const int t = w * 16 + i;
            if (t < T1) {
                const float bt = beta[t];
                cp.x = fmaf(bt, xr[i].x, cp.x);
                cp.y = fmaf(bt, xr[i].y, cp.y);
                cp.z = fmaf(bt, xr[i].z, cp.z);
                cp.w = fmaf(bt, xr[i].w, cp.w);
            }
        }
        ((float4*)cpart[w])[lane] = cp;
    }
    __syncthreads();
    float v = 0.f, vf = 0.f;
    if (tid < 256) {
        float ctx = 0.f;
        #pragma unroll
        for (int ww = 0; ww < 8; ++ww) ctx += cpart[ww][tid];
        v  = ctx * W_fc[tid];
        vf = ctx * W_final[256 + tid];
    }
    for (int m = 32; m >= 1; m >>= 1) {
        v  += __shfl_xor(v, m, 64);
        vf += __shfl_xor(vf, m, 64);
    }
    if (lane == 0) { wsum[w] = v; fsum[w] = vf; }
    __syncthreads();
    if (tid == 0) {
        su = wsum[0] + wsum[1] + wsum[2] + wsum[3] + b_fc[0];
        out[b] = fsum[0] + fsum[1] + fsum[2] + fsum[3] + b_final[0];
    }
    __syncthreads();
    const float wy = W_fc[256];
    if (tid < T1)
        ((float*)(ws + YT_OFF))[b * 128 + tid] = su + wy * y_prev[b * T1 + tid];
}

// ---------------- k_lstm: persistent sequential LSTM, epoch-in-data exchange ----------------
// R20-proven, byte-identical: R10 topology/prologue/t-loop (256 blocks,
// gi = bid>>3, hj = bid&7, Whi/Wlo staged fragments, serial 64-B line poll,
// two __syncthreads, publish-first) + t = T1 epilogue with LDS pre-reduction and
// ONE atomicAdd per batch per block (8-way contention).
__global__ __launch_bounds__(256, 1) void k_lstm(const float* __restrict__ W_ih,
                                                 const float* __restrict__ b_ih,
                                                 const float* __restrict__ b_hh,
                                                 const float* __restrict__ W_final,
                                                 float* __restrict__ out,
                                                 char* __restrict__ ws) {
    __shared__ __align__(16) ushort ldh[16 * 264];
    __shared__ __align__(16) ushort ldl[16 * 264];
    __shared__ float gbuf[16 * 132];

    const int tid = threadIdx.x, bid = blockIdx.x;
    const int gi = bid >> 3, hj = bid & 7;
    const int w = tid >> 6, lane = tid & 63;
    const int n16 = lane & 15, q = lane >> 4;

    const ushort* Whi = (const ushort*)(ws + WHI_OFF);
    const ushort* Wlo = (const ushort*)(ws + WLO_OFF);
    unsigned long long* Dbuf0 = (unsigned long long*)(ws + D0_OFF);
    unsigned long long* Dbuf1 = (unsigned long long*)(ws + D1_OFF);
    const float* yt = (const float*)(ws + YT_OFF);

    // resident W fragments: wave w owns N-tiles {2w, 2w+1}; row r = hloc*4 + g
    short8 bfh[2][8], bfl[2][8];
    #pragma unroll
    for (int j = 0; j < 2; ++j) {
        const int r = (2 * w + j) * 16 + n16;          // 0..127
        const int hloc = r >> 2, g = r & 3;
        const int R = g * 256 + hj * 32 + hloc;        // global gate row
        #pragma unroll
        for (int kt = 0; kt < 8; ++kt) {
            bfh[j][kt] = *(const short8*)(Whi + R * 256 + kt * 32 + q * 8);
            bfl[j][kt] = *(const short8*)(Wlo + R * 256 + kt * 32 + q * 8);
        }
    }

    // cell assignment: 16 batches x 32 h = 512 cells, 2 per thread
    const int b_loc = tid & 15, hpair = tid >> 4;      // hpair 0..15
    const int hloc0 = hpair * 2;
    const int bg = gi * 16 + b_loc;
    float wihr[2][4], bihr[2][4];
    #pragma unroll
    for (int jj = 0; jj < 2; ++jj)
        #pragma unroll
        for (int g = 0; g < 4; ++g) {
            const int row = g * HD + hj * 32 + hloc0 + jj;
            wihr[jj][g] = W_ih[row];
            bihr[jj][g] = b_ih[row] + b_hh[row];
        }
    float cc0 = 0.f, cc1 = 0.f;

    // poll/stage assignment: thread covers batch pb = tid>>4, hp8 = tid&15
    // words k = hp8*8 .. hp8*8+7 (cells h = 2k, 2k+1); origin block = hp8>>1
    const int pb = tid >> 4, hp8 = tid & 15;
    const bool own = ((hp8 >> 1) == hj);
    const size_t pbase = (size_t)(gi * 16 + pb) * 128 + hp8 * 8;   // 64B-aligned line

    // pre-zero this thread's full 16-ushort slab segment (d0 = 0) in BOTH planes
    {
        ushort8_t z = {0, 0, 0, 0, 0, 0, 0, 0};
        *(ushort8_t*)(ldh + pb * 264 + hp8 * 16)     = z;
        *(ushort8_t*)(ldh + pb * 264 + hp8 * 16 + 8) = z;
        *(ushort8_t*)(ldl + pb * 264 + hp8 * 16)     = z;
        *(ushort8_t*)(ldl + pb * 264 + hp8 * 16 + 8) = z;
    }

    for (int t = 1; t <= T1; ++t) {
        const float ytv = yt[bg * 128 + (t - 1)];   // prefetch, independent of d
        // ---- poll d_{t-1}: one 64-B line sample per round ----
        if (!own) {
            unsigned long long* Dsrc = ((t - 1) & 1) ? Dbuf1 : Dbuf0;
            const unsigned e = (unsigned)(t - 1) & 3u;
            unsigned lo[8], hi[8];
            for (int round = 0; ; ++round) {
                uint4 A, B, C, D;
                load64_ag(&Dsrc[pbase], A, B, C, D);
                lo[0] = A.x; hi[0] = A.y; lo[1] = A.z; hi[1] = A.w;
                lo[2] = B.x; hi[2] = B.y; lo[3] = B.z; hi[3] = B.w;
                lo[4] = C.x; hi[4] = C.y; lo[5] = C.z; hi[5] = C.w;
                lo[6] = D.x; hi[6] = D.y; lo[7] = D.z; hi[7] = D.w;
                bool ok = true;
                #pragma unroll
                for (int i = 0; i < 8; ++i) {
                    unsigned ep = (lo[i] & 1u) | ((hi[i] & 1u) << 1);
                    ok &= (ep == e);
                }
                if (ok) break;
                if (round >= 16) __builtin_amdgcn_s_sleep(1);
            }
            // decode: 16 hi + 16 lo ushorts -> two b128 stores per plane
            ushort hv[16], lv[16];
            #pragma unroll
            for (int i = 0; i < 8; ++i) {
                hv[2 * i]     = (ushort)(lo[i] >> 16);
                hv[2 * i + 1] = (ushort)(hi[i] >> 16);
                lv[2 * i]     = (ushort)(lo[i] & 0xFFFEu);
                lv[2 * i + 1] = (ushort)(hi[i] & 0xFFFEu);
            }
            ushort8_t H0, L0, H1, L1;
            #pragma unroll
            for (int i = 0; i < 8; ++i) { H0[i] = hv[i]; L0[i] = lv[i]; H1[i] = hv[8 + i]; L1[i] = lv[8 + i]; }
            *(ushort8_t*)(ldh + pb * 264 + hp8 * 16)     = H0;
            *(ushort8_t*)(ldh + pb * 264 + hp8 * 16 + 8) = H1;
            *(ushort8_t*)(ldl + pb * 264 + hp8 * 16)     = L0;
            *(ushort8_t*)(ldl + pb * 264 + hp8 * 16 + 8) = L1;
        }
        __syncthreads();
        // MFMA: gates[16b x 128r] = d[16x256] @ Wslice^T  (hi*hi + lo*hi + hi*lo)
        floatx4 acc0 = {0.f, 0.f, 0.f, 0.f}, acc1 = {0.f, 0.f, 0.f, 0.f};
        #pragma unroll
        for (int kt = 0; kt < 8; ++kt) {
            short8 ah = *(const short8*)(ldh + n16 * 264 + kt * 32 + q * 8);
            short8 al = *(const short8*)(ldl + n16 * 264 + kt * 32 + q * 8);
            acc0 = __builtin_amdgcn_mfma_f32_16x16x32_bf16(ah, bfh[0][kt], acc0, 0, 0, 0);
            acc0 = __builtin_amdgcn_mfma_f32_16x16x32_bf16(al, bfh[0][kt], acc0, 0, 0, 0);
            acc0 = __builtin_amdgcn_mfma_f32_16x16x32_bf16(ah, bfl[0][kt], acc0, 0, 0, 0);
            acc1 = __builtin_amdgcn_mfma_f32_16x16x32_bf16(ah, bfh[1][kt], acc1, 0, 0, 0);
            acc1 = __builtin_amdgcn_mfma_f32_16x16x32_bf16(al, bfh[1][kt], acc1, 0, 0, 0);
            acc1 = __builtin_amdgcn_mfma_f32_16x16x32_bf16(ah, bfl[1][kt], acc1, 0, 0, 0);
        }
        // scatter C-frags: row m = q*4+reg (batch), col = tile*16+n16 (gate row)
        #pragma unroll
        for (int reg = 0; reg < 4; ++reg) {
            gbuf[(q * 4 + reg) * 132 + (2 * w) * 16 + n16]     = acc0[reg];
            gbuf[(q * 4 + reg) * 132 + (2 * w + 1) * 16 + n16] = acc1[reg];
        }
        __syncthreads();
        // LSTM cell: 2 cells per thread
        float dnew[2];
        #pragma unroll
        for (int jj = 0; jj < 2; ++jj) {
            const int base = b_loc * 132 + (hloc0 + jj) * 4;
            float pi = gbuf[base + 0] + ytv * wihr[jj][0] + bihr[jj][0];
            float pf = gbuf[base + 1] + ytv * wihr[jj][1] + bihr[jj][1];
            float pg = gbuf[base + 2] + ytv * wihr[jj][2] + bihr[jj][2];
            float po = gbuf[base + 3] + ytv * wihr[jj][3] + bihr[jj][3];
            float ig = sigm_f(pi), fg = sigm_f(pf), og = sigm_f(po);
            float gg = tanh_f(pg);
            float& c = jj ? cc1 : cc0;
            c = fg * c + ig * gg;
            dnew[jj] = og * tanh_f(c);
        }
        if (t < T1) {
            const unsigned e = (unsigned)t & 3u;
            unsigned h0, l0, h1, l1;
            split_bf16(dnew[0], h0, l0);
            split_bf16(dnew[1], h1, l1);
            l0 = (l0 & 0xFFFEu) | (e & 1u);
            l1 = (l1 & 0xFFFEu) | ((e >> 1) & 1u);
            // publish FIRST (earliest visibility for the 7 consumer blocks)
            unsigned long long wv = ((unsigned long long)h1 << 48) |
                                    ((unsigned long long)l1 << 32) |
                                    ((unsigned long long)h0 << 16) |
                                    (unsigned long long)l0;
            unsigned long long* Ddst = (t & 1) ? Dbuf1 : Dbuf0;
            __hip_atomic_store(&Ddst[(size_t)bg * 128 + hj * 16 + hpair], wv,
                               __ATOMIC_RELAXED, __HIP_MEMORY_SCOPE_AGENT);
            // own slice -> directly into next step's LDS slab (barrier-ordered)
            *(ushort2*)(ldh + b_loc * 264 + hj * 32 + hloc0) =
                make_ushort2((ushort)h0, (ushort)h1);
            *(ushort2*)(ldl + b_loc * 264 + hj * 32 + hloc0) =
                make_ushort2((ushort)(l0 & 0xFFFEu), (ushort)(l1 & 0xFFFEu));
        } else {
            // fused k_final (dT half) with LDS pre-reduction: ONE atomicAdd per
            // batch per block (8-way contention across hj blocks).
            const float wf0 = W_final[hj * 32 + hloc0];
            const float wf1 = W_final[hj * 32 + hloc0 + 1];
            __syncthreads();   // all cell-phase gbuf reads complete (uniform branch)
            gbuf[hpair * 16 + b_loc] = dnew[0] * wf0 + dnew[1] * wf1;
            __syncthreads();
            if (tid < 16) {
                float s = 0.f;
                #pragma unroll
                for (int h = 0; h < 16; ++h) s += gbuf[h * 16 + tid];
                atomicAdd(out + gi * 16 + tid, s);
            }
        }
    }
}

extern "C" void kernel_launch(void* const* d_in, const int* in_sizes, int n_in,
                              void* d_out, int out_size, void* d_ws, size_t ws_size,
                              hipStream_t stream) {
    const float* X      = (const float*)d_in[0];
    const float* y_prev = (const float*)d_in[1];
    const float* W1     = (const float*)d_in[2];
    const float* W2     = (const float*)d_in[4];
    const float* W_fc   = (const float*)d_in[6];
    const float* b_fc   = (const float*)d_in[7];
    const float* W_ih   = (const float*)d_in[8];
    const float* W_hh   = (const float*)d_in[9];
    const float* b_ih   = (const float*)d_in[10];
    const float* b_hh   = (const float*)d_in[11];
    const float* W_fin  = (const float*)d_in[12];
    const float* b_fin  = (const float*)d_in[13];
    char* ws = (char*)d_ws;

    hipLaunchKernelGGL(k_attn, dim3(512), dim3(512), 0, stream,
                       X, y_prev, W1, W2, W_hh, W_fc, b_fc, W_fin, b_fin,
                       (float*)d_out, ws);
    hipLaunchKernelGGL(k_lstm, dim3(256), dim3(256), 0, stream,
                       W_ih, b_ih, b_hh, W_fin, (float*)d_out, ws);
}